// Round 1
// baseline (1521.692 us; speedup 1.0000x reference)
//
#include <hip/hip_runtime.h>
#include <cstdint>
#include <cstddef>

#define N1v 262144
#define E1v 1048576
#define N2v 9472
#define E2v 262144
#define BBv 64
#define RRv 148
#define HIDv 1000

static inline int cdiv(int a, int b) { return (a + b - 1) / b; }

// ---------------- graph prep ----------------
__global__ __launch_bounds__(256) void k_deg_scatter(const int* __restrict__ dst, const float* __restrict__ ew,
                                                     float* __restrict__ deg, int E) {
    int i = blockIdx.x * 256 + threadIdx.x;
    if (i < E) atomicAdd(&deg[dst[i]], ew[i]);
}

__global__ __launch_bounds__(256) void k_dinv(float* __restrict__ deg, int N) {
    int i = blockIdx.x * 256 + threadIdx.x;
    if (i < N) deg[i] = rsqrtf(deg[i] + 1.0f);
}

__global__ __launch_bounds__(256) void k_norm(const int* __restrict__ src, const int* __restrict__ dst,
                                              const float* __restrict__ ew, const float* __restrict__ dinv,
                                              float* __restrict__ norm, int E) {
    int i = blockIdx.x * 256 + threadIdx.x;
    if (i < E) norm[i] = dinv[src[i]] * ew[i] * dinv[dst[i]];
}

// ---------------- row-per-wave GEMM: Y(N,M) = op(X)(N,K) @ W(K,M) [+ bias][relu] ----------------
template<int MB, bool RIN, bool ROUT>
__global__ __launch_bounds__(256) void k_gemm_rowwave(const float* __restrict__ X, const float* __restrict__ W,
                                                      const float* __restrict__ bias, float* __restrict__ Y,
                                                      int N, int K) {
    extern __shared__ float Wl[];
    const int M = MB * 64;
    for (int idx = threadIdx.x; idx < K * M; idx += 256) Wl[idx] = W[idx];
    __syncthreads();
    int lane = threadIdx.x & 63;
    int gw = blockIdx.x * 4 + (threadIdx.x >> 6);
    int tw = gridDim.x * 4;
    const int K4 = K >> 2;
    for (int row = gw; row < N; row += tw) {
        float acc[MB];
#pragma unroll
        for (int cb = 0; cb < MB; ++cb) acc[cb] = 0.f;
        const float4* xr = (const float4*)(X + (size_t)row * K);
        for (int k4 = 0; k4 < K4; ++k4) {
            float4 xv = xr[k4];
            if (RIN) {
                xv.x = fmaxf(xv.x, 0.f); xv.y = fmaxf(xv.y, 0.f);
                xv.z = fmaxf(xv.z, 0.f); xv.w = fmaxf(xv.w, 0.f);
            }
            const float* wp = Wl + (k4 * 4) * M + lane;
#pragma unroll
            for (int cb = 0; cb < MB; ++cb) acc[cb] = fmaf(xv.x, wp[cb * 64], acc[cb]);
            wp += M;
#pragma unroll
            for (int cb = 0; cb < MB; ++cb) acc[cb] = fmaf(xv.y, wp[cb * 64], acc[cb]);
            wp += M;
#pragma unroll
            for (int cb = 0; cb < MB; ++cb) acc[cb] = fmaf(xv.z, wp[cb * 64], acc[cb]);
            wp += M;
#pragma unroll
            for (int cb = 0; cb < MB; ++cb) acc[cb] = fmaf(xv.w, wp[cb * 64], acc[cb]);
        }
#pragma unroll
        for (int cb = 0; cb < MB; ++cb) {
            float y = acc[cb];
            int col = cb * 64 + lane;
            if (bias) y += bias[col];
            if (ROUT) y = fmaxf(y, 0.f);
            Y[(size_t)row * M + col] = y;
        }
    }
}

// ---------------- self-loop init: A = P * dinv^2 + b ----------------
__global__ __launch_bounds__(256) void k_self_init(const float* __restrict__ P, const float* __restrict__ dinv,
                                                   const float* __restrict__ bias, float* __restrict__ A, int N) {
    int gid = blockIdx.x * 256 + threadIdx.x;
    if (gid >= N * 16) return;
    int row = gid >> 4, c4 = gid & 15;
    float di = dinv[row];
    float s = di * di;
    float4 p = ((const float4*)P)[gid];
    float4 b = ((const float4*)bias)[c4];
    float4 r;
    r.x = fmaf(p.x, s, b.x); r.y = fmaf(p.y, s, b.y);
    r.z = fmaf(p.z, s, b.z); r.w = fmaf(p.w, s, b.w);
    ((float4*)A)[gid] = r;
}

// ---------------- edge scatter: A[dst] += P[src] * norm ----------------
__global__ __launch_bounds__(256) void k_edge_scatter(const int* __restrict__ src, const int* __restrict__ dst,
                                                      const float* __restrict__ norm, const float* __restrict__ P,
                                                      float* __restrict__ A, int E) {
    int lane = threadIdx.x & 63;
    int gw = blockIdx.x * 4 + (threadIdx.x >> 6);
    int tw = gridDim.x * 4;
    for (int e = gw; e < E; e += tw) {
        int s = src[e], d = dst[e];
        float nv = norm[e];
        float v = P[(size_t)s * 64 + lane] * nv;
        atomicAdd(&A[(size_t)d * 64 + lane], v);
    }
}

// ---------------- ROI pool: scatter-mean of relu(A) by (batch,roi) ----------------
__global__ __launch_bounds__(256) void k_pool_scatter(const float* __restrict__ Ain, const int* __restrict__ roi,
                                                      const int* __restrict__ batch, float* __restrict__ sums,
                                                      float* __restrict__ cnt, int N) {
    int lane = threadIdx.x & 63;
    int gw = blockIdx.x * 4 + (threadIdx.x >> 6);
    int tw = gridDim.x * 4;
    for (int i = gw; i < N; i += tw) {
        int seg = batch[i] * RRv + roi[i];
        float v = fmaxf(Ain[(size_t)i * 64 + lane], 0.f);
        atomicAdd(&sums[(size_t)seg * 64 + lane], v);
        if (lane == 0) atomicAdd(&cnt[seg], 1.f);
    }
}

__global__ __launch_bounds__(256) void k_pool_fin(const float* __restrict__ sums, const float* __restrict__ cnt,
                                                  float* __restrict__ outp, int total) {
    int i = blockIdx.x * 256 + threadIdx.x;
    if (i < total) outp[i] = sums[i] / fmaxf(cnt[i >> 6], 1.f);
}

// ---------------- elementwise add (float4) ----------------
__global__ __launch_bounds__(256) void k_add4(const float* __restrict__ a, const float* __restrict__ b,
                                              float* __restrict__ c, int n4) {
    int i = blockIdx.x * 256 + threadIdx.x;
    if (i < n4) {
        float4 x = ((const float4*)a)[i], y = ((const float4*)b)[i];
        float4 r; r.x = x.x + y.x; r.y = x.y + y.y; r.z = x.z + y.z; r.w = x.w + y.w;
        ((float4*)c)[i] = r;
    }
}

// ---------------- transpose W(rows,cols) -> Wt(cols,rows) ----------------
__global__ __launch_bounds__(256) void k_transpose(const float* __restrict__ W, float* __restrict__ Wt,
                                                   int rows, int cols) {
    int i = blockIdx.x * 256 + threadIdx.x;
    if (i < rows * cols) {
        int r = i / cols, c = i - r * cols;
        Wt[c * rows + r] = W[i];
    }
}

// ---------------- attention: one block per (b,h) ----------------
__global__ __launch_bounds__(256) void k_attn(const float* __restrict__ qkv, float* __restrict__ aw,
                                              float* __restrict__ o) {
    int bh = blockIdx.x;
    int b = bh >> 2, h = bh & 3;
    __shared__ float qs[148][16];
    __shared__ float kT[16][152];
    __shared__ float vs[148][16];
    __shared__ float ps[4][152];
    int tid = threadIdx.x;
    const float* base = qkv + (size_t)b * 148 * 192 + h * 16;
    for (int idx = tid; idx < 148 * 16; idx += 256) {
        int i = idx >> 4, d = idx & 15;
        const float* p = base + (size_t)i * 192 + d;
        qs[i][d] = p[0] * 0.25f;   // fold 1/sqrt(16)
        kT[d][i] = p[64];
        vs[i][d] = p[128];
    }
    __syncthreads();
    int wv = tid >> 6, lane = tid & 63;
    float* aw_bh = aw + (size_t)bh * 148 * 148;
    for (int i = wv; i < 148; i += 4) {
        float s0 = 0.f, s1 = 0.f, s2 = 0.f;
#pragma unroll
        for (int d = 0; d < 16; ++d) {
            float q = qs[i][d];
            s0 = fmaf(q, kT[d][lane], s0);
            s1 = fmaf(q, kT[d][lane + 64], s1);
            if (lane < 20) s2 = fmaf(q, kT[d][lane + 128], s2);
        }
        float m = fmaxf(s0, s1);
        if (lane < 20) m = fmaxf(m, s2);
#pragma unroll
        for (int off = 1; off < 64; off <<= 1) m = fmaxf(m, __shfl_xor(m, off));
        float e0 = __expf(s0 - m), e1 = __expf(s1 - m);
        float e2 = (lane < 20) ? __expf(s2 - m) : 0.f;
        float sum = e0 + e1 + e2;
#pragma unroll
        for (int off = 1; off < 64; off <<= 1) sum += __shfl_xor(sum, off);
        float inv = 1.f / sum;
        float p0 = e0 * inv, p1 = e1 * inv, p2 = e2 * inv;
        float* awr = aw_bh + (size_t)i * 148;
        awr[lane] = p0;
        awr[lane + 64] = p1;
        if (lane < 20) awr[lane + 128] = p2;
        ps[wv][lane] = p0;
        ps[wv][lane + 64] = p1;
        if (lane < 20) ps[wv][lane + 128] = p2;
        // PV: lane = (jj,d)
        int d = lane & 15, jj = lane >> 4;
        float acc = 0.f;
        for (int t = jj; t < 148; t += 4) acc = fmaf(ps[wv][t], vs[t][d], acc);
        acc += __shfl_xor(acc, 16);
        acc += __shfl_xor(acc, 32);
        if (lane < 16) o[((size_t)b * 148 + i) * 64 + h * 16 + d] = acc;
    }
}

// ---------------- fused GEMM + bias + residual + LayerNorm (K=M=64) ----------------
__global__ __launch_bounds__(256) void k_ln_gemm(const float* __restrict__ X, const float* __restrict__ Wt,
                                                 const float* __restrict__ bias, const float* __restrict__ resid,
                                                 const float* __restrict__ g, const float* __restrict__ bb,
                                                 float* __restrict__ Y, int N) {
    __shared__ float Wl[4096];
    for (int idx = threadIdx.x; idx < 4096; idx += 256) Wl[idx] = Wt[idx];
    __syncthreads();
    int lane = threadIdx.x & 63;
    int gw = blockIdx.x * 4 + (threadIdx.x >> 6);
    int tw = gridDim.x * 4;
    for (int row = gw; row < N; row += tw) {
        const float4* xr = (const float4*)(X + (size_t)row * 64);
        float acc = 0.f;
        for (int k4 = 0; k4 < 16; ++k4) {
            float4 xv = xr[k4];
            const float* wp = Wl + (k4 * 4) * 64 + lane;
            acc = fmaf(xv.x, wp[0], acc);
            acc = fmaf(xv.y, wp[64], acc);
            acc = fmaf(xv.z, wp[128], acc);
            acc = fmaf(xv.w, wp[192], acc);
        }
        float y = acc + bias[lane] + resid[(size_t)row * 64 + lane];
        float s = y;
#pragma unroll
        for (int off = 1; off < 64; off <<= 1) s += __shfl_xor(s, off);
        float mu = s * (1.f / 64.f);
        float dcen = y - mu;
        float v = dcen * dcen;
#pragma unroll
        for (int off = 1; off < 64; off <<= 1) v += __shfl_xor(v, off);
        float var = v * (1.f / 64.f);
        Y[(size_t)row * 64 + lane] = dcen * rsqrtf(var + 1e-5f) * g[lane] + bb[lane];
    }
}

// ---------------- classifier GEMM: Z(64,1000) += T(64,9472) @ Wc1(9472,1000), split-K ----------------
__global__ __launch_bounds__(256) void k_cls_gemm(const float* __restrict__ T, const float* __restrict__ Wc1,
                                                  float* __restrict__ Z) {
    __shared__ float Tl[64][74];
    int mt = blockIdx.x & 15;
    int ks = blockIdx.x >> 4;
    int m0 = mt * 64;
    int k0 = ks * 592;
    int tid = threadIdx.x;
    int lane = tid & 63, bq = tid >> 6;
    int m = m0 + lane;
    bool mvalid = m < 1000;
    float acc[16];
#pragma unroll
    for (int j = 0; j < 16; ++j) acc[j] = 0.f;
    for (int ch = 0; ch < 8; ++ch) {
        int kb = k0 + ch * 74;
        __syncthreads();
        for (int idx = tid; idx < 64 * 74; idx += 256) {
            int bb = idx / 74, kk = idx - bb * 74;
            Tl[bb][kk] = T[(size_t)bb * 9472 + kb + kk];
        }
        __syncthreads();
        for (int kk = 0; kk < 74; ++kk) {
            float w = mvalid ? Wc1[(size_t)(kb + kk) * 1000 + m] : 0.f;
#pragma unroll
            for (int j = 0; j < 16; ++j) acc[j] = fmaf(Tl[bq * 16 + j][kk], w, acc[j]);
        }
    }
    if (mvalid) {
#pragma unroll
        for (int j = 0; j < 16; ++j) atomicAdd(&Z[(size_t)(bq * 16 + j) * 1000 + m], acc[j]);
    }
}

// ---------------- classifier finish: bias + BN(eval) + leaky + @Wc2 + bc2 ----------------
__global__ __launch_bounds__(256) void k_cls_final(const float* __restrict__ Z, const float* __restrict__ bc1,
                                                   const float* __restrict__ bn_g, const float* __restrict__ bn_b,
                                                   const float* __restrict__ Wc2, const float* __restrict__ bc2,
                                                   float* __restrict__ out) {
    int b = blockIdx.x;
    int tid = threadIdx.x;
    float rs = rsqrtf(1.0f + 1e-5f);
    float a0 = 0.f, a1 = 0.f;
    for (int m = tid; m < 1000; m += 256) {
        float z = Z[b * 1000 + m] + bc1[m];
        z = bn_g[m] * z * rs + bn_b[m];
        z = z >= 0.f ? z : 0.01f * z;
        a0 = fmaf(z, Wc2[m * 2], a0);
        a1 = fmaf(z, Wc2[m * 2 + 1], a1);
    }
#pragma unroll
    for (int off = 1; off < 64; off <<= 1) {
        a0 += __shfl_xor(a0, off);
        a1 += __shfl_xor(a1, off);
    }
    __shared__ float r0[4], r1[4];
    if ((tid & 63) == 0) { r0[tid >> 6] = a0; r1[tid >> 6] = a1; }
    __syncthreads();
    if (tid == 0) {
        out[b * 2 + 0] = r0[0] + r0[1] + r0[2] + r0[3] + bc2[0];
        out[b * 2 + 1] = r1[0] + r1[1] + r1[2] + r1[3] + bc2[1];
    }
}

extern "C" void kernel_launch(void* const* d_in, const int* in_sizes, int n_in,
                              void* d_out, int out_size, void* d_ws, size_t ws_size,
                              hipStream_t stream) {
    (void)in_sizes; (void)n_in; (void)out_size; (void)ws_size;

    const float* x_feat = (const float*)d_in[0];
    const int* node_roi = (const int*)d_in[1];
    const int* batch1 = (const int*)d_in[2];
    const int* ei1 = (const int*)d_in[3];
    const float* ew1 = (const float*)d_in[4];
    const float* x2f = (const float*)d_in[5];
    const int* roi2 = (const int*)d_in[6];
    const int* batch2 = (const int*)d_in[7];
    const int* ei2 = (const int*)d_in[8];
    const float* ew2 = (const float*)d_in[9];
    const float* Wg1 = (const float*)d_in[10];
    const float* bg1 = (const float*)d_in[11];
    const float* Wg2 = (const float*)d_in[12];
    const float* bg2 = (const float*)d_in[13];
    const float* Wr1 = (const float*)d_in[14];
    const float* br1 = (const float*)d_in[15];
    const float* Wr2 = (const float*)d_in[16];
    const float* br2 = (const float*)d_in[17];
    const float* in_proj_w = (const float*)d_in[18];
    const float* in_proj_b = (const float*)d_in[19];
    const float* out_proj_w = (const float*)d_in[20];
    const float* out_proj_b = (const float*)d_in[21];
    const float* ln1_g = (const float*)d_in[22];
    const float* ln1_b = (const float*)d_in[23];
    const float* ff_w1 = (const float*)d_in[24];
    const float* ff_b1 = (const float*)d_in[25];
    const float* ff_w2 = (const float*)d_in[26];
    const float* ff_b2 = (const float*)d_in[27];
    const float* ln2_g = (const float*)d_in[28];
    const float* ln2_b = (const float*)d_in[29];
    const float* Wc1 = (const float*)d_in[30];
    const float* bc1 = (const float*)d_in[31];
    const float* bn_g = (const float*)d_in[32];
    const float* bn_b = (const float*)d_in[33];
    const float* Wc2 = (const float*)d_in[34];
    const float* bc2 = (const float*)d_in[35];

    const int* src1 = ei1;
    const int* dst1 = ei1 + E1v;
    const int* src2 = ei2;
    const int* dst2 = ei2 + E2v;

    float* out = (float*)d_out;
    const int PSZ = BBv * RRv * 64;        // 606208
    float* pooled_out = out + 128;
    float* pooledroi_out = out + 128 + PSZ;
    float* tout_out = out + 128 + 2 * PSZ;
    float* attn_out = out + 128 + 3 * PSZ;

    // workspace layout (floats)
    float* W = (float*)d_ws;
    float* h1P = W;                          size_t o = (size_t)N1v * 64;
    float* h1A = W + o;                      o += (size_t)N1v * 64;
    float* dinv1 = W + o;                    o += N1v;
    float* norm1 = W + o;                    o += E1v;
    float* h2P = W + o;                      o += (size_t)N2v * 64;
    float* h2A = W + o;                      o += (size_t)N2v * 64;
    float* dinv2 = W + o;                    o += N2v;
    float* norm2 = W + o;                    o += E2v;
    float* sums = W + o;                     o += PSZ;
    float* cnt = W + o;                      o += BBv * RRv;
    float* comb = W + o;                     o += PSZ;
    float* qkvb = W + o;                     o += (size_t)BBv * RRv * 192;
    float* obuf = W + o;                     o += PSZ;
    float* xbuf = W + o;                     o += PSZ;
    float* f1 = W + o;                       o += PSZ;
    float* zbuf = W + o;                     o += BBv * HIDv;
    float* WinT = W + o;                     o += 64 * 192;
    float* WoutT = W + o;                    o += 64 * 64;

    dim3 blk(256);

    // ===== branch 1 (node graph) =====
    hipMemsetAsync(dinv1, 0, (size_t)N1v * 4, stream);
    k_deg_scatter<<<cdiv(E1v, 256), blk, 0, stream>>>(dst1, ew1, dinv1, E1v);
    k_dinv<<<cdiv(N1v, 256), blk, 0, stream>>>(dinv1, N1v);
    k_norm<<<cdiv(E1v, 256), blk, 0, stream>>>(src1, dst1, ew1, dinv1, norm1, E1v);
    k_gemm_rowwave<1, false, false><<<4096, blk, 64 * 64 * 4, stream>>>(x_feat, Wg1, nullptr, h1P, N1v, 64);
    k_self_init<<<cdiv(N1v * 16, 256), blk, 0, stream>>>(h1P, dinv1, bg1, h1A, N1v);
    k_edge_scatter<<<8192, blk, 0, stream>>>(src1, dst1, norm1, h1P, h1A, E1v);
    k_gemm_rowwave<1, true, false><<<4096, blk, 64 * 64 * 4, stream>>>(h1A, Wg2, nullptr, h1P, N1v, 64);
    k_self_init<<<cdiv(N1v * 16, 256), blk, 0, stream>>>(h1P, dinv1, bg2, h1A, N1v);
    k_edge_scatter<<<8192, blk, 0, stream>>>(src1, dst1, norm1, h1P, h1A, E1v);
    hipMemsetAsync(sums, 0, (size_t)(PSZ + BBv * RRv) * 4, stream);
    k_pool_scatter<<<8192, blk, 0, stream>>>(h1A, node_roi, batch1, sums, cnt, N1v);
    k_pool_fin<<<cdiv(PSZ, 256), blk, 0, stream>>>(sums, cnt, pooled_out, PSZ);

    // ===== branch 2 (roi graph) =====
    hipMemsetAsync(dinv2, 0, (size_t)N2v * 4, stream);
    k_deg_scatter<<<cdiv(E2v, 256), blk, 0, stream>>>(dst2, ew2, dinv2, E2v);
    k_dinv<<<cdiv(N2v, 256), blk, 0, stream>>>(dinv2, N2v);
    k_norm<<<cdiv(E2v, 256), blk, 0, stream>>>(src2, dst2, ew2, dinv2, norm2, E2v);
    k_gemm_rowwave<1, false, false><<<cdiv(N2v, 4), blk, 148 * 64 * 4, stream>>>(x2f, Wr1, nullptr, h2P, N2v, 148);
    k_self_init<<<cdiv(N2v * 16, 256), blk, 0, stream>>>(h2P, dinv2, br1, h2A, N2v);
    k_edge_scatter<<<2048, blk, 0, stream>>>(src2, dst2, norm2, h2P, h2A, E2v);
    k_gemm_rowwave<1, true, false><<<cdiv(N2v, 4), blk, 64 * 64 * 4, stream>>>(h2A, Wr2, nullptr, h2P, N2v, 64);
    k_self_init<<<cdiv(N2v * 16, 256), blk, 0, stream>>>(h2P, dinv2, br2, h2A, N2v);
    k_edge_scatter<<<2048, blk, 0, stream>>>(src2, dst2, norm2, h2P, h2A, E2v);
    hipMemsetAsync(sums, 0, (size_t)(PSZ + BBv * RRv) * 4, stream);
    k_pool_scatter<<<2048, blk, 0, stream>>>(h2A, roi2, batch2, sums, cnt, N2v);
    k_pool_fin<<<cdiv(PSZ, 256), blk, 0, stream>>>(sums, cnt, pooledroi_out, PSZ);

    // ===== transformer =====
    k_add4<<<cdiv(PSZ / 4, 256), blk, 0, stream>>>(pooled_out, pooledroi_out, comb, PSZ / 4);
    k_transpose<<<cdiv(192 * 64, 256), blk, 0, stream>>>(in_proj_w, WinT, 192, 64);
    k_transpose<<<cdiv(64 * 64, 256), blk, 0, stream>>>(out_proj_w, WoutT, 64, 64);
    k_gemm_rowwave<3, false, false><<<cdiv(N2v, 4), blk, 64 * 192 * 4, stream>>>(comb, WinT, in_proj_b, qkvb, N2v, 64);
    k_attn<<<BBv * 4, blk, 0, stream>>>(qkvb, attn_out, obuf);
    k_ln_gemm<<<cdiv(N2v, 4), blk, 0, stream>>>(obuf, WoutT, out_proj_b, comb, ln1_g, ln1_b, xbuf, N2v);
    k_gemm_rowwave<1, false, true><<<cdiv(N2v, 4), blk, 64 * 64 * 4, stream>>>(xbuf, ff_w1, ff_b1, f1, N2v, 64);
    k_ln_gemm<<<cdiv(N2v, 4), blk, 0, stream>>>(f1, ff_w2, ff_b2, xbuf, ln2_g, ln2_b, tout_out, N2v);

    // ===== classifier =====
    hipMemsetAsync(zbuf, 0, (size_t)BBv * HIDv * 4, stream);
    k_cls_gemm<<<256, blk, 0, stream>>>(tout_out, Wc1, zbuf);
    k_cls_final<<<BBv, blk, 0, stream>>>(zbuf, bc1, bn_g, bn_b, Wc2, bc2, out);
}

// Round 2
// 1309.579 us; speedup vs baseline: 1.1620x; 1.1620x over previous
//
#include <hip/hip_runtime.h>
#include <cstdint>
#include <cstddef>

#define N1v 262144
#define E1v 1048576
#define N2v 9472
#define E2v 262144
#define BBv 64
#define RRv 148
#define HIDv 1000
#define BRv (BBv * RRv)

static inline int cdiv(int a, int b) { return (a + b - 1) / b; }

// ---------------- fused degree + histogram ----------------
__global__ __launch_bounds__(256) void k_deg_hist(const int* __restrict__ dst, const float* __restrict__ ew,
                                                  float* __restrict__ deg, int* __restrict__ counts, int E) {
    int i = blockIdx.x * 256 + threadIdx.x;
    if (i < E) {
        int d = dst[i];
        atomicAdd(&deg[d], ew[i]);
        atomicAdd(&counts[d], 1);
    }
}

__global__ __launch_bounds__(256) void k_dinv(float* __restrict__ deg, int N) {
    int i = blockIdx.x * 256 + threadIdx.x;
    if (i < N) deg[i] = rsqrtf(deg[i] + 1.0f);
}

// ---------------- 3-kernel exclusive scan (1024 elems/block) ----------------
__global__ __launch_bounds__(256) void k_scan1(const int* __restrict__ counts, int* __restrict__ offs,
                                               int* __restrict__ aux, int N) {
    __shared__ int tmp[256];
    int t = threadIdx.x;
    int base = blockIdx.x * 1024 + t * 4;
    int v0 = 0, v1 = 0, v2 = 0, v3 = 0;
    if (base + 3 < N) {
        int4 c = *(const int4*)(counts + base);
        v0 = c.x; v1 = c.y; v2 = c.z; v3 = c.w;
    } else {
        if (base < N) v0 = counts[base];
        if (base + 1 < N) v1 = counts[base + 1];
        if (base + 2 < N) v2 = counts[base + 2];
    }
    int tsum = v0 + v1 + v2 + v3;
    tmp[t] = tsum;
    __syncthreads();
    int val = tsum;
    for (int off = 1; off < 256; off <<= 1) {
        int other = (t >= off) ? tmp[t - off] : 0;
        __syncthreads();
        val += other;
        tmp[t] = val;
        __syncthreads();
    }
    int excl = val - tsum;
    if (base < N) offs[base] = excl;
    if (base + 1 < N) offs[base + 1] = excl + v0;
    if (base + 2 < N) offs[base + 2] = excl + v0 + v1;
    if (base + 3 < N) offs[base + 3] = excl + v0 + v1 + v2;
    if (t == 255) aux[blockIdx.x] = val;
}

__global__ __launch_bounds__(256) void k_scan2(int* __restrict__ aux, int nb) {
    __shared__ int tmp[256];
    int t = threadIdx.x;
    int v = (t < nb) ? aux[t] : 0;
    tmp[t] = v;
    __syncthreads();
    int val = v;
    for (int off = 1; off < 256; off <<= 1) {
        int other = (t >= off) ? tmp[t - off] : 0;
        __syncthreads();
        val += other;
        tmp[t] = val;
        __syncthreads();
    }
    if (t < nb) aux[t] = val - v;
}

__global__ __launch_bounds__(256) void k_scan3(int* __restrict__ offs, const int* __restrict__ aux,
                                               int* __restrict__ cursor, int N) {
    int i = blockIdx.x * 256 + threadIdx.x;
    if (i < N) {
        int val = offs[i] + aux[i >> 10];
        offs[i] = val;
        cursor[i] = val;
    }
}

// ---------------- CSR fill (+ fused sym-norm computation) ----------------
__global__ __launch_bounds__(256) void k_fill(const int* __restrict__ src, const int* __restrict__ dst,
                                              const float* __restrict__ ew, const float* __restrict__ dinv,
                                              int* __restrict__ cursor, int* __restrict__ srcC,
                                              float* __restrict__ normC, int E) {
    int e = blockIdx.x * 256 + threadIdx.x;
    if (e < E) {
        int s = src[e], d = dst[e];
        float nv = dinv[s] * ew[e] * dinv[d];
        int j = atomicAdd(&cursor[d], 1);
        srcC[j] = s;
        normC[j] = nv;
    }
}

// ---------------- edge gather: A[i] = sum_{e in csr[i]} P[src]*norm + P[i]*dinv^2 + b ----------------
__global__ __launch_bounds__(256) void k_edge_gather(const int* __restrict__ srcC, const float* __restrict__ normC,
                                                     const int* __restrict__ offs, const float* __restrict__ P,
                                                     const float* __restrict__ dinv, const float* __restrict__ bias,
                                                     float* __restrict__ A, int N, int E) {
    int lane = threadIdx.x & 63;
    int gw = blockIdx.x * 4 + (threadIdx.x >> 6);
    int tw = gridDim.x * 4;
    for (int i = gw; i < N; i += tw) {
        int beg = offs[i];
        int end = (i + 1 < N) ? offs[i + 1] : E;
        float di = dinv[i];
        float acc = fmaf(P[(size_t)i * 64 + lane], di * di, bias[lane]);
        for (int j = beg; j < end; ++j) {
            int s = srcC[j];
            float nv = normC[j];
            acc = fmaf(P[(size_t)s * 64 + lane], nv, acc);
        }
        A[(size_t)i * 64 + lane] = acc;
    }
}

// ---------------- row-per-wave GEMM: Y(N,M) = op(X)(N,K) @ W(K,M) [+ bias][relu] ----------------
template<int MB, bool RIN, bool ROUT>
__global__ __launch_bounds__(256) void k_gemm_rowwave(const float* __restrict__ X, const float* __restrict__ W,
                                                      const float* __restrict__ bias, float* __restrict__ Y,
                                                      int N, int K) {
    extern __shared__ float Wl[];
    const int M = MB * 64;
    for (int idx = threadIdx.x; idx < K * M; idx += 256) Wl[idx] = W[idx];
    __syncthreads();
    int lane = threadIdx.x & 63;
    int gw = blockIdx.x * 4 + (threadIdx.x >> 6);
    int tw = gridDim.x * 4;
    const int K4 = K >> 2;
    for (int row = gw; row < N; row += tw) {
        float acc[MB];
#pragma unroll
        for (int cb = 0; cb < MB; ++cb) acc[cb] = 0.f;
        const float4* xr = (const float4*)(X + (size_t)row * K);
        for (int k4 = 0; k4 < K4; ++k4) {
            float4 xv = xr[k4];
            if (RIN) {
                xv.x = fmaxf(xv.x, 0.f); xv.y = fmaxf(xv.y, 0.f);
                xv.z = fmaxf(xv.z, 0.f); xv.w = fmaxf(xv.w, 0.f);
            }
            const float* wp = Wl + (k4 * 4) * M + lane;
#pragma unroll
            for (int cb = 0; cb < MB; ++cb) acc[cb] = fmaf(xv.x, wp[cb * 64], acc[cb]);
            wp += M;
#pragma unroll
            for (int cb = 0; cb < MB; ++cb) acc[cb] = fmaf(xv.y, wp[cb * 64], acc[cb]);
            wp += M;
#pragma unroll
            for (int cb = 0; cb < MB; ++cb) acc[cb] = fmaf(xv.z, wp[cb * 64], acc[cb]);
            wp += M;
#pragma unroll
            for (int cb = 0; cb < MB; ++cb) acc[cb] = fmaf(xv.w, wp[cb * 64], acc[cb]);
        }
#pragma unroll
        for (int cb = 0; cb < MB; ++cb) {
            float y = acc[cb];
            int col = cb * 64 + lane;
            if (bias) y += bias[col];
            if (ROUT) y = fmaxf(y, 0.f);
            Y[(size_t)row * M + col] = y;
        }
    }
}

// ---------------- ROI pool partials: LDS accumulate per (graph, part), merge to global ----------------
__global__ __launch_bounds__(256) void k_pool_part(const float* __restrict__ A, const int* __restrict__ roi,
                                                   float* __restrict__ sums, float* __restrict__ cnt,
                                                   int npg, int bpg) {
    int b = blockIdx.x / bpg;
    int part = blockIdx.x - b * bpg;
    __shared__ float ls[RRv * 64];
    __shared__ int lc[RRv];
    int tid = threadIdx.x;
    for (int idx = tid; idx < RRv * 64; idx += 256) ls[idx] = 0.f;
    for (int idx = tid; idx < RRv; idx += 256) lc[idx] = 0;
    __syncthreads();
    int wv = tid >> 6, lane = tid & 63;
    int wig = part * 4 + wv, stride = bpg * 4;
    for (int i = wig; i < npg; i += stride) {
        int node = b * npg + i;
        int r = roi[node];
        atomicAdd(&ls[r * 64 + lane], fmaxf(A[(size_t)node * 64 + lane], 0.f));
        if (lane == 0) atomicAdd(&lc[r], 1);
    }
    __syncthreads();
    float* sb = sums + (size_t)b * RRv * 64;
    for (int idx = tid; idx < RRv * 64; idx += 256) {
        float v = ls[idx];
        if (v != 0.f) atomicAdd(&sb[idx], v);
    }
    for (int idx = tid; idx < RRv; idx += 256) {
        int c = lc[idx];
        if (c) atomicAdd(&cnt[b * RRv + idx], (float)c);
    }
}

__global__ __launch_bounds__(256) void k_pool_fin(const float* __restrict__ sums, const float* __restrict__ cnt,
                                                  float* __restrict__ outp, int total) {
    int i = blockIdx.x * 256 + threadIdx.x;
    if (i < total) outp[i] = sums[i] / fmaxf(cnt[i >> 6], 1.f);
}

// fin for branch2: also emits comb = pooled_roi + pooled
__global__ __launch_bounds__(256) void k_pool_fin2(const float* __restrict__ sums, const float* __restrict__ cnt,
                                                   const float* __restrict__ other, float* __restrict__ outp,
                                                   float* __restrict__ comb, int total) {
    int i = blockIdx.x * 256 + threadIdx.x;
    if (i < total) {
        float v = sums[i] / fmaxf(cnt[i >> 6], 1.f);
        outp[i] = v;
        comb[i] = v + other[i];
    }
}

// ---------------- transpose W(rows,cols) -> Wt(cols,rows) ----------------
__global__ __launch_bounds__(256) void k_transpose(const float* __restrict__ W, float* __restrict__ Wt,
                                                   int rows, int cols) {
    int i = blockIdx.x * 256 + threadIdx.x;
    if (i < rows * cols) {
        int r = i / cols, c = i - r * cols;
        Wt[c * rows + r] = W[i];
    }
}

// ---------------- attention: one block per (b,h) ----------------
__global__ __launch_bounds__(256) void k_attn(const float* __restrict__ qkv, float* __restrict__ aw,
                                              float* __restrict__ o) {
    int bh = blockIdx.x;
    int b = bh >> 2, h = bh & 3;
    __shared__ float qs[148][16];
    __shared__ float kT[16][152];
    __shared__ float vs[148][16];
    __shared__ float ps[4][152];
    int tid = threadIdx.x;
    const float* base = qkv + (size_t)b * 148 * 192 + h * 16;
    for (int idx = tid; idx < 148 * 16; idx += 256) {
        int i = idx >> 4, d = idx & 15;
        const float* p = base + (size_t)i * 192 + d;
        qs[i][d] = p[0] * 0.25f;   // fold 1/sqrt(16)
        kT[d][i] = p[64];
        vs[i][d] = p[128];
    }
    __syncthreads();
    int wv = tid >> 6, lane = tid & 63;
    float* aw_bh = aw + (size_t)bh * 148 * 148;
    for (int i = wv; i < 148; i += 4) {
        float s0 = 0.f, s1 = 0.f, s2 = 0.f;
#pragma unroll
        for (int d = 0; d < 16; ++d) {
            float q = qs[i][d];
            s0 = fmaf(q, kT[d][lane], s0);
            s1 = fmaf(q, kT[d][lane + 64], s1);
            if (lane < 20) s2 = fmaf(q, kT[d][lane + 128], s2);
        }
        float m = fmaxf(s0, s1);
        if (lane < 20) m = fmaxf(m, s2);
#pragma unroll
        for (int off = 1; off < 64; off <<= 1) m = fmaxf(m, __shfl_xor(m, off));
        float e0 = __expf(s0 - m), e1 = __expf(s1 - m);
        float e2 = (lane < 20) ? __expf(s2 - m) : 0.f;
        float sum = e0 + e1 + e2;
#pragma unroll
        for (int off = 1; off < 64; off <<= 1) sum += __shfl_xor(sum, off);
        float inv = 1.f / sum;
        float p0 = e0 * inv, p1 = e1 * inv, p2 = e2 * inv;
        float* awr = aw_bh + (size_t)i * 148;
        awr[lane] = p0;
        awr[lane + 64] = p1;
        if (lane < 20) awr[lane + 128] = p2;
        ps[wv][lane] = p0;
        ps[wv][lane + 64] = p1;
        if (lane < 20) ps[wv][lane + 128] = p2;
        int d = lane & 15, jj = lane >> 4;
        float acc = 0.f;
        for (int t = jj; t < 148; t += 4) acc = fmaf(ps[wv][t], vs[t][d], acc);
        acc += __shfl_xor(acc, 16);
        acc += __shfl_xor(acc, 32);
        if (lane < 16) o[((size_t)b * 148 + i) * 64 + h * 16 + d] = acc;
    }
}

// ---------------- fused GEMM + bias + residual + LayerNorm (K=M=64) ----------------
__global__ __launch_bounds__(256) void k_ln_gemm(const float* __restrict__ X, const float* __restrict__ Wt,
                                                 const float* __restrict__ bias, const float* __restrict__ resid,
                                                 const float* __restrict__ g, const float* __restrict__ bb,
                                                 float* __restrict__ Y, int N) {
    __shared__ float Wl[4096];
    for (int idx = threadIdx.x; idx < 4096; idx += 256) Wl[idx] = Wt[idx];
    __syncthreads();
    int lane = threadIdx.x & 63;
    int gw = blockIdx.x * 4 + (threadIdx.x >> 6);
    int tw = gridDim.x * 4;
    for (int row = gw; row < N; row += tw) {
        const float4* xr = (const float4*)(X + (size_t)row * 64);
        float acc = 0.f;
        for (int k4 = 0; k4 < 16; ++k4) {
            float4 xv = xr[k4];
            const float* wp = Wl + (k4 * 4) * 64 + lane;
            acc = fmaf(xv.x, wp[0], acc);
            acc = fmaf(xv.y, wp[64], acc);
            acc = fmaf(xv.z, wp[128], acc);
            acc = fmaf(xv.w, wp[192], acc);
        }
        float y = acc + bias[lane] + resid[(size_t)row * 64 + lane];
        float s = y;
#pragma unroll
        for (int off = 1; off < 64; off <<= 1) s += __shfl_xor(s, off);
        float mu = s * (1.f / 64.f);
        float dcen = y - mu;
        float v = dcen * dcen;
#pragma unroll
        for (int off = 1; off < 64; off <<= 1) v += __shfl_xor(v, off);
        float var = v * (1.f / 64.f);
        Y[(size_t)row * 64 + lane] = dcen * rsqrtf(var + 1e-5f) * g[lane] + bb[lane];
    }
}

// ---------------- classifier GEMM: Z(64,1000) += T(64,9472) @ Wc1(9472,1000), split-K ----------------
__global__ __launch_bounds__(256) void k_cls_gemm(const float* __restrict__ T, const float* __restrict__ Wc1,
                                                  float* __restrict__ Z) {
    __shared__ float Tl[64][74];
    int mt = blockIdx.x & 15;
    int ks = blockIdx.x >> 4;
    int m0 = mt * 64;
    int k0 = ks * 592;
    int tid = threadIdx.x;
    int lane = tid & 63, bq = tid >> 6;
    int m = m0 + lane;
    bool mvalid = m < 1000;
    float acc[16];
#pragma unroll
    for (int j = 0; j < 16; ++j) acc[j] = 0.f;
    for (int ch = 0; ch < 8; ++ch) {
        int kb = k0 + ch * 74;
        __syncthreads();
        for (int idx = tid; idx < 64 * 74; idx += 256) {
            int bb = idx / 74, kk = idx - bb * 74;
            Tl[bb][kk] = T[(size_t)bb * 9472 + kb + kk];
        }
        __syncthreads();
        for (int kk = 0; kk < 74; ++kk) {
            float w = mvalid ? Wc1[(size_t)(kb + kk) * 1000 + m] : 0.f;
#pragma unroll
            for (int j = 0; j < 16; ++j) acc[j] = fmaf(Tl[bq * 16 + j][kk], w, acc[j]);
        }
    }
    if (mvalid) {
#pragma unroll
        for (int j = 0; j < 16; ++j) atomicAdd(&Z[(size_t)(bq * 16 + j) * 1000 + m], acc[j]);
    }
}

// ---------------- classifier finish ----------------
__global__ __launch_bounds__(256) void k_cls_final(const float* __restrict__ Z, const float* __restrict__ bc1,
                                                   const float* __restrict__ bn_g, const float* __restrict__ bn_b,
                                                   const float* __restrict__ Wc2, const float* __restrict__ bc2,
                                                   float* __restrict__ out) {
    int b = blockIdx.x;
    int tid = threadIdx.x;
    float rs = rsqrtf(1.0f + 1e-5f);
    float a0 = 0.f, a1 = 0.f;
    for (int m = tid; m < 1000; m += 256) {
        float z = Z[b * 1000 + m] + bc1[m];
        z = bn_g[m] * z * rs + bn_b[m];
        z = z >= 0.f ? z : 0.01f * z;
        a0 = fmaf(z, Wc2[m * 2], a0);
        a1 = fmaf(z, Wc2[m * 2 + 1], a1);
    }
#pragma unroll
    for (int off = 1; off < 64; off <<= 1) {
        a0 += __shfl_xor(a0, off);
        a1 += __shfl_xor(a1, off);
    }
    __shared__ float r0[4], r1[4];
    if ((tid & 63) == 0) { r0[tid >> 6] = a0; r1[tid >> 6] = a1; }
    __syncthreads();
    if (tid == 0) {
        out[b * 2 + 0] = r0[0] + r0[1] + r0[2] + r0[3] + bc2[0];
        out[b * 2 + 1] = r1[0] + r1[1] + r1[2] + r1[3] + bc2[1];
    }
}

extern "C" void kernel_launch(void* const* d_in, const int* in_sizes, int n_in,
                              void* d_out, int out_size, void* d_ws, size_t ws_size,
                              hipStream_t stream) {
    (void)in_sizes; (void)n_in; (void)out_size; (void)ws_size;

    const float* x_feat = (const float*)d_in[0];
    const int* node_roi = (const int*)d_in[1];
    const int* ei1 = (const int*)d_in[3];
    const float* ew1 = (const float*)d_in[4];
    const float* x2f = (const float*)d_in[5];
    const int* roi2 = (const int*)d_in[6];
    const int* ei2 = (const int*)d_in[8];
    const float* ew2 = (const float*)d_in[9];
    const float* Wg1 = (const float*)d_in[10];
    const float* bg1 = (const float*)d_in[11];
    const float* Wg2 = (const float*)d_in[12];
    const float* bg2 = (const float*)d_in[13];
    const float* Wr1 = (const float*)d_in[14];
    const float* br1 = (const float*)d_in[15];
    const float* Wr2 = (const float*)d_in[16];
    const float* br2 = (const float*)d_in[17];
    const float* in_proj_w = (const float*)d_in[18];
    const float* in_proj_b = (const float*)d_in[19];
    const float* out_proj_w = (const float*)d_in[20];
    const float* out_proj_b = (const float*)d_in[21];
    const float* ln1_g = (const float*)d_in[22];
    const float* ln1_b = (const float*)d_in[23];
    const float* ff_w1 = (const float*)d_in[24];
    const float* ff_b1 = (const float*)d_in[25];
    const float* ff_w2 = (const float*)d_in[26];
    const float* ff_b2 = (const float*)d_in[27];
    const float* ln2_g = (const float*)d_in[28];
    const float* ln2_b = (const float*)d_in[29];
    const float* Wc1 = (const float*)d_in[30];
    const float* bc1 = (const float*)d_in[31];
    const float* bn_g = (const float*)d_in[32];
    const float* bn_b = (const float*)d_in[33];
    const float* Wc2 = (const float*)d_in[34];
    const float* bc2 = (const float*)d_in[35];

    const int* src1 = ei1;
    const int* dst1 = ei1 + E1v;
    const int* src2 = ei2;
    const int* dst2 = ei2 + E2v;

    float* out = (float*)d_out;
    const int PSZ = BRv * 64;              // 606208
    float* pooled_out = out + 128;
    float* pooledroi_out = out + 128 + PSZ;
    float* tout_out = out + 128 + 2 * PSZ;
    float* attn_out = out + 128 + 3 * PSZ;

    // ===== workspace layout (floats) =====
    float* W = (float*)d_ws;
    size_t o = 0;
    // zero-zone (single memset)
    float* dinv1 = W + o;       o += N1v;
    int* counts1 = (int*)(W + o); o += N1v;
    float* dinv2 = W + o;       o += N2v;
    int* counts2 = (int*)(W + o); o += N2v;
    float* sums1 = W + o;       o += PSZ;
    float* cnt1 = W + o;        o += BRv;
    float* sums2 = W + o;       o += PSZ;
    float* cnt2 = W + o;        o += BRv;
    float* zbuf = W + o;        o += BBv * HIDv;
    size_t zone_elems = o;
    // non-zeroed scratch
    int* offs1 = (int*)(W + o); o += N1v;
    int* aux1 = (int*)(W + o);  o += 256;
    int* srcC1 = (int*)(W + o); o += E1v;
    float* normC1 = W + o;      o += E1v;
    int* offs2 = (int*)(W + o); o += N2v;
    int* aux2 = (int*)(W + o);  o += 256;
    int* srcC2 = (int*)(W + o); o += E2v;
    float* normC2 = W + o;      o += E2v;
    float* h1P = W + o; size_t h1P_off = o; o += (size_t)N1v * 64;
    float* h1A = W + o;         o += (size_t)N1v * 64;
    // pack aliased onto h1P region (branch1 fully done before these are touched)
    size_t p = h1P_off;
    float* h2P = W + p;  p += (size_t)N2v * 64;
    float* h2A = W + p;  p += (size_t)N2v * 64;
    float* comb = W + p; p += PSZ;
    float* qkvb = W + p; p += (size_t)BRv * 192;
    float* obuf = W + p; p += PSZ;
    float* xbuf = W + p; p += PSZ;
    float* f1 = W + p;   p += PSZ;
    float* WinT = W + p; p += 64 * 192;
    float* WoutT = W + p; p += 64 * 64;

    dim3 blk(256);

    hipMemsetAsync(W, 0, zone_elems * sizeof(float), stream);

    // ===== branch 1 (node graph): CSR build =====
    k_deg_hist<<<E1v / 256, blk, 0, stream>>>(dst1, ew1, dinv1, counts1, E1v);
    k_dinv<<<N1v / 256, blk, 0, stream>>>(dinv1, N1v);
    k_scan1<<<N1v / 1024, blk, 0, stream>>>(counts1, offs1, aux1, N1v);
    k_scan2<<<1, blk, 0, stream>>>(aux1, N1v / 1024);
    k_scan3<<<N1v / 256, blk, 0, stream>>>(offs1, aux1, counts1, N1v);
    k_fill<<<E1v / 256, blk, 0, stream>>>(src1, dst1, ew1, dinv1, counts1, srcC1, normC1, E1v);
    // layers
    k_gemm_rowwave<1, false, false><<<4096, blk, 64 * 64 * 4, stream>>>(x_feat, Wg1, nullptr, h1P, N1v, 64);
    k_edge_gather<<<4096, blk, 0, stream>>>(srcC1, normC1, offs1, h1P, dinv1, bg1, h1A, N1v, E1v);
    k_gemm_rowwave<1, true, false><<<4096, blk, 64 * 64 * 4, stream>>>(h1A, Wg2, nullptr, h1P, N1v, 64);
    k_edge_gather<<<4096, blk, 0, stream>>>(srcC1, normC1, offs1, h1P, dinv1, bg2, h1A, N1v, E1v);
    k_pool_part<<<BBv * 4, blk, 0, stream>>>(h1A, node_roi, sums1, cnt1, N1v / BBv, 4);
    k_pool_fin<<<cdiv(PSZ, 256), blk, 0, stream>>>(sums1, cnt1, pooled_out, PSZ);

    // ===== branch 2 (roi graph): CSR build =====
    k_deg_hist<<<E2v / 256, blk, 0, stream>>>(dst2, ew2, dinv2, counts2, E2v);
    k_dinv<<<cdiv(N2v, 256), blk, 0, stream>>>(dinv2, N2v);
    k_scan1<<<cdiv(N2v, 1024), blk, 0, stream>>>(counts2, offs2, aux2, N2v);
    k_scan2<<<1, blk, 0, stream>>>(aux2, cdiv(N2v, 1024));
    k_scan3<<<cdiv(N2v, 256), blk, 0, stream>>>(offs2, aux2, counts2, N2v);
    k_fill<<<E2v / 256, blk, 0, stream>>>(src2, dst2, ew2, dinv2, counts2, srcC2, normC2, E2v);
    // layers
    k_gemm_rowwave<1, false, false><<<cdiv(N2v, 4), blk, 148 * 64 * 4, stream>>>(x2f, Wr1, nullptr, h2P, N2v, 148);
    k_edge_gather<<<cdiv(N2v, 4), blk, 0, stream>>>(srcC2, normC2, offs2, h2P, dinv2, br1, h2A, N2v, E2v);
    k_gemm_rowwave<1, true, false><<<cdiv(N2v, 4), blk, 64 * 64 * 4, stream>>>(h2A, Wr2, nullptr, h2P, N2v, 64);
    k_edge_gather<<<cdiv(N2v, 4), blk, 0, stream>>>(srcC2, normC2, offs2, h2P, dinv2, br2, h2A, N2v, E2v);
    k_pool_part<<<BBv, blk, 0, stream>>>(h2A, roi2, sums2, cnt2, RRv, 1);
    k_pool_fin2<<<cdiv(PSZ, 256), blk, 0, stream>>>(sums2, cnt2, pooled_out, pooledroi_out, comb, PSZ);

    // ===== transformer =====
    k_transpose<<<cdiv(192 * 64, 256), blk, 0, stream>>>(in_proj_w, WinT, 192, 64);
    k_transpose<<<cdiv(64 * 64, 256), blk, 0, stream>>>(out_proj_w, WoutT, 64, 64);
    k_gemm_rowwave<3, false, false><<<cdiv(N2v, 4), blk, 64 * 192 * 4, stream>>>(comb, WinT, in_proj_b, qkvb, N2v, 64);
    k_attn<<<BBv * 4, blk, 0, stream>>>(qkvb, attn_out, obuf);
    k_ln_gemm<<<cdiv(N2v, 4), blk, 0, stream>>>(obuf, WoutT, out_proj_b, comb, ln1_g, ln1_b, xbuf, N2v);
    k_gemm_rowwave<1, false, true><<<cdiv(N2v, 4), blk, 64 * 64 * 4, stream>>>(xbuf, ff_w1, ff_b1, f1, N2v, 64);
    k_ln_gemm<<<cdiv(N2v, 4), blk, 0, stream>>>(f1, ff_w2, ff_b2, xbuf, ln2_g, ln2_b, tout_out, N2v);

    // ===== classifier =====
    k_cls_gemm<<<256, blk, 0, stream>>>(tout_out, Wc1, zbuf);
    k_cls_final<<<BBv, blk, 0, stream>>>(zbuf, bc1, bn_g, bn_b, Wc2, bc2, out);
}

// Round 3
// 1180.607 us; speedup vs baseline: 1.2889x; 1.1092x over previous
//
#include <hip/hip_runtime.h>
#include <cstdint>
#include <cstddef>

#define N1v 262144
#define E1v 1048576
#define N2v 9472
#define E2v 262144
#define BBv 64
#define RRv 148
#define HIDv 1000
#define BRv (BBv * RRv)

static inline int cdiv(int a, int b) { return (a + b - 1) / b; }

// ---------------- fused degree + histogram ----------------
__global__ __launch_bounds__(256) void k_deg_hist(const int* __restrict__ dst, const float* __restrict__ ew,
                                                  float* __restrict__ deg, int* __restrict__ counts, int E) {
    int i = blockIdx.x * 256 + threadIdx.x;
    if (i < E) {
        int d = dst[i];
        atomicAdd(&deg[d], ew[i]);
        atomicAdd(&counts[d], 1);
    }
}

__global__ __launch_bounds__(256) void k_dinv(float* __restrict__ deg, int N) {
    int i = blockIdx.x * 256 + threadIdx.x;
    if (i < N) deg[i] = rsqrtf(deg[i] + 1.0f);
}

// ---------------- 3-kernel exclusive scan (1024 elems/block) ----------------
__global__ __launch_bounds__(256) void k_scan1(const int* __restrict__ counts, int* __restrict__ offs,
                                               int* __restrict__ aux, int N) {
    __shared__ int tmp[256];
    int t = threadIdx.x;
    int base = blockIdx.x * 1024 + t * 4;
    int v0 = 0, v1 = 0, v2 = 0, v3 = 0;
    if (base + 3 < N) {
        int4 c = *(const int4*)(counts + base);
        v0 = c.x; v1 = c.y; v2 = c.z; v3 = c.w;
    } else {
        if (base < N) v0 = counts[base];
        if (base + 1 < N) v1 = counts[base + 1];
        if (base + 2 < N) v2 = counts[base + 2];
    }
    int tsum = v0 + v1 + v2 + v3;
    tmp[t] = tsum;
    __syncthreads();
    int val = tsum;
    for (int off = 1; off < 256; off <<= 1) {
        int other = (t >= off) ? tmp[t - off] : 0;
        __syncthreads();
        val += other;
        tmp[t] = val;
        __syncthreads();
    }
    int excl = val - tsum;
    if (base < N) offs[base] = excl;
    if (base + 1 < N) offs[base + 1] = excl + v0;
    if (base + 2 < N) offs[base + 2] = excl + v0 + v1;
    if (base + 3 < N) offs[base + 3] = excl + v0 + v1 + v2;
    if (t == 255) aux[blockIdx.x] = val;
}

__global__ __launch_bounds__(256) void k_scan2(int* __restrict__ aux, int nb) {
    __shared__ int tmp[256];
    int t = threadIdx.x;
    int v = (t < nb) ? aux[t] : 0;
    tmp[t] = v;
    __syncthreads();
    int val = v;
    for (int off = 1; off < 256; off <<= 1) {
        int other = (t >= off) ? tmp[t - off] : 0;
        __syncthreads();
        val += other;
        tmp[t] = val;
        __syncthreads();
    }
    if (t < nb) aux[t] = val - v;
}

__global__ __launch_bounds__(256) void k_scan3(int* __restrict__ offs, const int* __restrict__ aux,
                                               int* __restrict__ cursor, int N) {
    int i = blockIdx.x * 256 + threadIdx.x;
    if (i < N) {
        int val = offs[i] + aux[i >> 10];
        offs[i] = val;
        cursor[i] = val;
    }
}

// ---------------- CSR fill (+ fused sym-norm computation) ----------------
__global__ __launch_bounds__(256) void k_fill(const int* __restrict__ src, const int* __restrict__ dst,
                                              const float* __restrict__ ew, const float* __restrict__ dinv,
                                              int* __restrict__ cursor, int* __restrict__ srcC,
                                              float* __restrict__ normC, int E) {
    int e = blockIdx.x * 256 + threadIdx.x;
    if (e < E) {
        int s = src[e], d = dst[e];
        float nv = dinv[s] * ew[e] * dinv[d];
        int j = atomicAdd(&cursor[d], 1);
        srcC[j] = s;
        normC[j] = nv;
    }
}

// ---------------- edge gather: A[i] = sum_{e in csr[i]} P[src]*norm + P[i]*dinv^2 + b ----------------
__global__ __launch_bounds__(256) void k_edge_gather(const int* __restrict__ srcC, const float* __restrict__ normC,
                                                     const int* __restrict__ offs, const float* __restrict__ P,
                                                     const float* __restrict__ dinv, const float* __restrict__ bias,
                                                     float* __restrict__ A, int N, int E) {
    int lane = threadIdx.x & 63;
    int gw = blockIdx.x * 4 + (threadIdx.x >> 6);
    int tw = gridDim.x * 4;
    for (int i = gw; i < N; i += tw) {
        int beg = offs[i];
        int end = (i + 1 < N) ? offs[i + 1] : E;
        float di = dinv[i];
        float acc = fmaf(P[(size_t)i * 64 + lane], di * di, bias[lane]);
        for (int j = beg; j < end; ++j) {
            int s = srcC[j];
            float nv = normC[j];
            acc = fmaf(P[(size_t)s * 64 + lane], nv, acc);
        }
        A[(size_t)i * 64 + lane] = acc;
    }
}

// ---------------- row-per-wave GEMM: Y(N,M) = op(X)(N,K) @ W(K,M) [+ bias][relu] ----------------
template<int MB, bool RIN, bool ROUT>
__global__ __launch_bounds__(256) void k_gemm_rowwave(const float* __restrict__ X, const float* __restrict__ W,
                                                      const float* __restrict__ bias, float* __restrict__ Y,
                                                      int N, int K) {
    extern __shared__ float Wl[];
    const int M = MB * 64;
    for (int idx = threadIdx.x; idx < K * M; idx += 256) Wl[idx] = W[idx];
    __syncthreads();
    int lane = threadIdx.x & 63;
    int gw = blockIdx.x * 4 + (threadIdx.x >> 6);
    int tw = gridDim.x * 4;
    const int K4 = K >> 2;
    for (int row = gw; row < N; row += tw) {
        float acc[MB];
#pragma unroll
        for (int cb = 0; cb < MB; ++cb) acc[cb] = 0.f;
        const float4* xr = (const float4*)(X + (size_t)row * K);
        for (int k4 = 0; k4 < K4; ++k4) {
            float4 xv = xr[k4];
            if (RIN) {
                xv.x = fmaxf(xv.x, 0.f); xv.y = fmaxf(xv.y, 0.f);
                xv.z = fmaxf(xv.z, 0.f); xv.w = fmaxf(xv.w, 0.f);
            }
            const float* wp = Wl + (k4 * 4) * M + lane;
#pragma unroll
            for (int cb = 0; cb < MB; ++cb) acc[cb] = fmaf(xv.x, wp[cb * 64], acc[cb]);
            wp += M;
#pragma unroll
            for (int cb = 0; cb < MB; ++cb) acc[cb] = fmaf(xv.y, wp[cb * 64], acc[cb]);
            wp += M;
#pragma unroll
            for (int cb = 0; cb < MB; ++cb) acc[cb] = fmaf(xv.z, wp[cb * 64], acc[cb]);
            wp += M;
#pragma unroll
            for (int cb = 0; cb < MB; ++cb) acc[cb] = fmaf(xv.w, wp[cb * 64], acc[cb]);
        }
#pragma unroll
        for (int cb = 0; cb < MB; ++cb) {
            float y = acc[cb];
            int col = cb * 64 + lane;
            if (bias) y += bias[col];
            if (ROUT) y = fmaxf(y, 0.f);
            Y[(size_t)row * M + col] = y;
        }
    }
}

// ---------------- ROI pool partials: LDS accumulate per (graph, part), merge to global ----------------
__global__ __launch_bounds__(256) void k_pool_part(const float* __restrict__ A, const int* __restrict__ roi,
                                                   float* __restrict__ sums, float* __restrict__ cnt,
                                                   int npg, int bpg) {
    int b = blockIdx.x / bpg;
    int part = blockIdx.x - b * bpg;
    __shared__ float ls[RRv * 64];
    __shared__ int lc[RRv];
    int tid = threadIdx.x;
    for (int idx = tid; idx < RRv * 64; idx += 256) ls[idx] = 0.f;
    for (int idx = tid; idx < RRv; idx += 256) lc[idx] = 0;
    __syncthreads();
    int wv = tid >> 6, lane = tid & 63;
    int wig = part * 4 + wv, stride = bpg * 4;
    for (int i = wig; i < npg; i += stride) {
        int node = b * npg + i;
        int r = roi[node];
        atomicAdd(&ls[r * 64 + lane], fmaxf(A[(size_t)node * 64 + lane], 0.f));
        if (lane == 0) atomicAdd(&lc[r], 1);
    }
    __syncthreads();
    float* sb = sums + (size_t)b * RRv * 64;
    for (int idx = tid; idx < RRv * 64; idx += 256) {
        float v = ls[idx];
        if (v != 0.f) atomicAdd(&sb[idx], v);
    }
    for (int idx = tid; idx < RRv; idx += 256) {
        int c = lc[idx];
        if (c) atomicAdd(&cnt[b * RRv + idx], (float)c);
    }
}

__global__ __launch_bounds__(256) void k_pool_fin(const float* __restrict__ sums, const float* __restrict__ cnt,
                                                  float* __restrict__ outp, int total) {
    int i = blockIdx.x * 256 + threadIdx.x;
    if (i < total) outp[i] = sums[i] / fmaxf(cnt[i >> 6], 1.f);
}

// fin for branch2: also emits comb = pooled_roi + pooled
__global__ __launch_bounds__(256) void k_pool_fin2(const float* __restrict__ sums, const float* __restrict__ cnt,
                                                   const float* __restrict__ other, float* __restrict__ outp,
                                                   float* __restrict__ comb, int total) {
    int i = blockIdx.x * 256 + threadIdx.x;
    if (i < total) {
        float v = sums[i] / fmaxf(cnt[i >> 6], 1.f);
        outp[i] = v;
        comb[i] = v + other[i];
    }
}

// ---------------- transpose W(rows,cols) -> Wt(cols,rows) ----------------
__global__ __launch_bounds__(256) void k_transpose(const float* __restrict__ W, float* __restrict__ Wt,
                                                   int rows, int cols) {
    int i = blockIdx.x * 256 + threadIdx.x;
    if (i < rows * cols) {
        int r = i / cols, c = i - r * cols;
        Wt[c * rows + r] = W[i];
    }
}

// ---------------- attention: one block per (b,h) ----------------
__global__ __launch_bounds__(256) void k_attn(const float* __restrict__ qkv, float* __restrict__ aw,
                                              float* __restrict__ o) {
    int bh = blockIdx.x;
    int b = bh >> 2, h = bh & 3;
    __shared__ float qs[148][16];
    __shared__ float kT[16][152];
    __shared__ float vs[148][16];
    __shared__ float ps[4][152];
    int tid = threadIdx.x;
    const float* base = qkv + (size_t)b * 148 * 192 + h * 16;
    for (int idx = tid; idx < 148 * 16; idx += 256) {
        int i = idx >> 4, d = idx & 15;
        const float* p = base + (size_t)i * 192 + d;
        qs[i][d] = p[0] * 0.25f;   // fold 1/sqrt(16)
        kT[d][i] = p[64];
        vs[i][d] = p[128];
    }
    __syncthreads();
    int wv = tid >> 6, lane = tid & 63;
    float* aw_bh = aw + (size_t)bh * 148 * 148;
    for (int i = wv; i < 148; i += 4) {
        float s0 = 0.f, s1 = 0.f, s2 = 0.f;
#pragma unroll
        for (int d = 0; d < 16; ++d) {
            float q = qs[i][d];
            s0 = fmaf(q, kT[d][lane], s0);
            s1 = fmaf(q, kT[d][lane + 64], s1);
            if (lane < 20) s2 = fmaf(q, kT[d][lane + 128], s2);
        }
        float m = fmaxf(s0, s1);
        if (lane < 20) m = fmaxf(m, s2);
#pragma unroll
        for (int off = 1; off < 64; off <<= 1) m = fmaxf(m, __shfl_xor(m, off));
        float e0 = __expf(s0 - m), e1 = __expf(s1 - m);
        float e2 = (lane < 20) ? __expf(s2 - m) : 0.f;
        float sum = e0 + e1 + e2;
#pragma unroll
        for (int off = 1; off < 64; off <<= 1) sum += __shfl_xor(sum, off);
        float inv = 1.f / sum;
        float p0 = e0 * inv, p1 = e1 * inv, p2 = e2 * inv;
        float* awr = aw_bh + (size_t)i * 148;
        awr[lane] = p0;
        awr[lane + 64] = p1;
        if (lane < 20) awr[lane + 128] = p2;
        ps[wv][lane] = p0;
        ps[wv][lane + 64] = p1;
        if (lane < 20) ps[wv][lane + 128] = p2;
        int d = lane & 15, jj = lane >> 4;
        float acc = 0.f;
        for (int t = jj; t < 148; t += 4) acc = fmaf(ps[wv][t], vs[t][d], acc);
        acc += __shfl_xor(acc, 16);
        acc += __shfl_xor(acc, 32);
        if (lane < 16) o[((size_t)b * 148 + i) * 64 + h * 16 + d] = acc;
    }
}

// ---------------- fused GEMM + bias + residual + LayerNorm (K=M=64) ----------------
__global__ __launch_bounds__(256) void k_ln_gemm(const float* __restrict__ X, const float* __restrict__ Wt,
                                                 const float* __restrict__ bias, const float* __restrict__ resid,
                                                 const float* __restrict__ g, const float* __restrict__ bb,
                                                 float* __restrict__ Y, int N) {
    __shared__ float Wl[4096];
    for (int idx = threadIdx.x; idx < 4096; idx += 256) Wl[idx] = Wt[idx];
    __syncthreads();
    int lane = threadIdx.x & 63;
    int gw = blockIdx.x * 4 + (threadIdx.x >> 6);
    int tw = gridDim.x * 4;
    for (int row = gw; row < N; row += tw) {
        const float4* xr = (const float4*)(X + (size_t)row * 64);
        float acc = 0.f;
        for (int k4 = 0; k4 < 16; ++k4) {
            float4 xv = xr[k4];
            const float* wp = Wl + (k4 * 4) * 64 + lane;
            acc = fmaf(xv.x, wp[0], acc);
            acc = fmaf(xv.y, wp[64], acc);
            acc = fmaf(xv.z, wp[128], acc);
            acc = fmaf(xv.w, wp[192], acc);
        }
        float y = acc + bias[lane] + resid[(size_t)row * 64 + lane];
        float s = y;
#pragma unroll
        for (int off = 1; off < 64; off <<= 1) s += __shfl_xor(s, off);
        float mu = s * (1.f / 64.f);
        float dcen = y - mu;
        float v = dcen * dcen;
#pragma unroll
        for (int off = 1; off < 64; off <<= 1) v += __shfl_xor(v, off);
        float var = v * (1.f / 64.f);
        Y[(size_t)row * 64 + lane] = dcen * rsqrtf(var + 1e-5f) * g[lane] + bb[lane];
    }
}

// ---------------- classifier stage A: partial GEMM, no atomics ----------------
// grid = 128 ksplits * 4 mtiles; Zp[ks][64][1024]
__global__ __launch_bounds__(256) void k_cls_part(const float* __restrict__ T, const float* __restrict__ Wc1,
                                                  float* __restrict__ Zp) {
    int ks = blockIdx.x >> 2;
    int mt = blockIdx.x & 3;
    int k0 = ks * 74;
    int m0 = mt * 256;
    __shared__ float Tl[64][74];
    int tid = threadIdx.x;
    for (int idx = tid; idx < 64 * 74; idx += 256) {
        int b = idx / 74, kk = idx - b * 74;
        Tl[b][kk] = T[(size_t)b * 9472 + k0 + kk];
    }
    __syncthreads();
    int lane = tid & 63, bq = tid >> 6;
    int mbase = m0 + lane * 4;
    // clamp for memory safety on the last m-tile (those values are ignored downstream)
    size_t moff = (mbase + 3 < 1000) ? (size_t)mbase : 0;
    float4 acc[16];
#pragma unroll
    for (int j = 0; j < 16; ++j) acc[j] = make_float4(0.f, 0.f, 0.f, 0.f);
#pragma unroll 2
    for (int kk = 0; kk < 74; ++kk) {
        float4 w = *(const float4*)(Wc1 + (size_t)(k0 + kk) * 1000 + moff);
#pragma unroll
        for (int j = 0; j < 16; ++j) {
            float t = Tl[bq * 16 + j][kk];
            acc[j].x = fmaf(t, w.x, acc[j].x);
            acc[j].y = fmaf(t, w.y, acc[j].y);
            acc[j].z = fmaf(t, w.z, acc[j].z);
            acc[j].w = fmaf(t, w.w, acc[j].w);
        }
    }
    float* zp = Zp + (size_t)ks * 64 * 1024;
#pragma unroll
    for (int j = 0; j < 16; ++j) {
        int b = bq * 16 + j;
        *(float4*)(zp + (size_t)b * 1024 + mbase) = acc[j];
    }
}

// ---------------- classifier stage B: reduce partials + bias + BN + leaky ----------------
__global__ __launch_bounds__(256) void k_cls_reduce(const float* __restrict__ Zp, const float* __restrict__ bc1,
                                                    const float* __restrict__ bn_g, const float* __restrict__ bn_b,
                                                    float* __restrict__ zb) {
    int flat = blockIdx.x * 256 + threadIdx.x;   // 64*1024
    int b = flat >> 10, m = flat & 1023;
    if (m >= 1000) return;
    float s = 0.f;
    for (int ks = 0; ks < 128; ++ks)
        s += Zp[((size_t)ks * 64 + b) * 1024 + m];
    float rs = rsqrtf(1.0f + 1e-5f);
    float z = bn_g[m] * (s + bc1[m]) * rs + bn_b[m];
    zb[flat] = z >= 0.f ? z : 0.01f * z;
}

// ---------------- classifier finish: 1000 -> 2 matvec ----------------
__global__ __launch_bounds__(256) void k_cls_final(const float* __restrict__ zb,
                                                   const float* __restrict__ Wc2, const float* __restrict__ bc2,
                                                   float* __restrict__ out) {
    int b = blockIdx.x;
    int tid = threadIdx.x;
    float a0 = 0.f, a1 = 0.f;
    for (int m = tid; m < 1000; m += 256) {
        float z = zb[b * 1024 + m];
        a0 = fmaf(z, Wc2[m * 2], a0);
        a1 = fmaf(z, Wc2[m * 2 + 1], a1);
    }
#pragma unroll
    for (int off = 1; off < 64; off <<= 1) {
        a0 += __shfl_xor(a0, off);
        a1 += __shfl_xor(a1, off);
    }
    __shared__ float r0[4], r1[4];
    if ((tid & 63) == 0) { r0[tid >> 6] = a0; r1[tid >> 6] = a1; }
    __syncthreads();
    if (tid == 0) {
        out[b * 2 + 0] = r0[0] + r0[1] + r0[2] + r0[3] + bc2[0];
        out[b * 2 + 1] = r1[0] + r1[1] + r1[2] + r1[3] + bc2[1];
    }
}

extern "C" void kernel_launch(void* const* d_in, const int* in_sizes, int n_in,
                              void* d_out, int out_size, void* d_ws, size_t ws_size,
                              hipStream_t stream) {
    (void)in_sizes; (void)n_in; (void)out_size; (void)ws_size;

    const float* x_feat = (const float*)d_in[0];
    const int* node_roi = (const int*)d_in[1];
    const int* ei1 = (const int*)d_in[3];
    const float* ew1 = (const float*)d_in[4];
    const float* x2f = (const float*)d_in[5];
    const int* roi2 = (const int*)d_in[6];
    const int* ei2 = (const int*)d_in[8];
    const float* ew2 = (const float*)d_in[9];
    const float* Wg1 = (const float*)d_in[10];
    const float* bg1 = (const float*)d_in[11];
    const float* Wg2 = (const float*)d_in[12];
    const float* bg2 = (const float*)d_in[13];
    const float* Wr1 = (const float*)d_in[14];
    const float* br1 = (const float*)d_in[15];
    const float* Wr2 = (const float*)d_in[16];
    const float* br2 = (const float*)d_in[17];
    const float* in_proj_w = (const float*)d_in[18];
    const float* in_proj_b = (const float*)d_in[19];
    const float* out_proj_w = (const float*)d_in[20];
    const float* out_proj_b = (const float*)d_in[21];
    const float* ln1_g = (const float*)d_in[22];
    const float* ln1_b = (const float*)d_in[23];
    const float* ff_w1 = (const float*)d_in[24];
    const float* ff_b1 = (const float*)d_in[25];
    const float* ff_w2 = (const float*)d_in[26];
    const float* ff_b2 = (const float*)d_in[27];
    const float* ln2_g = (const float*)d_in[28];
    const float* ln2_b = (const float*)d_in[29];
    const float* Wc1 = (const float*)d_in[30];
    const float* bc1 = (const float*)d_in[31];
    const float* bn_g = (const float*)d_in[32];
    const float* bn_b = (const float*)d_in[33];
    const float* Wc2 = (const float*)d_in[34];
    const float* bc2 = (const float*)d_in[35];

    const int* src1 = ei1;
    const int* dst1 = ei1 + E1v;
    const int* src2 = ei2;
    const int* dst2 = ei2 + E2v;

    float* out = (float*)d_out;
    const int PSZ = BRv * 64;              // 606208
    float* pooled_out = out + 128;
    float* pooledroi_out = out + 128 + PSZ;
    float* tout_out = out + 128 + 2 * PSZ;
    float* attn_out = out + 128 + 3 * PSZ;

    // ===== workspace layout (floats) =====
    float* W = (float*)d_ws;
    size_t o = 0;
    // zero-zone (single memset)
    float* dinv1 = W + o;       o += N1v;
    int* counts1 = (int*)(W + o); o += N1v;
    float* dinv2 = W + o;       o += N2v;
    int* counts2 = (int*)(W + o); o += N2v;
    float* sums1 = W + o;       o += PSZ;
    float* cnt1 = W + o;        o += BRv;
    float* sums2 = W + o;       o += PSZ;
    float* cnt2 = W + o;        o += BRv;
    float* zbuf = W + o;        o += BBv * 1024;
    size_t zone_elems = o;
    // non-zeroed scratch
    int* offs1 = (int*)(W + o); o += N1v;
    int* aux1 = (int*)(W + o);  o += 256;
    int* srcC1 = (int*)(W + o); o += E1v;
    float* normC1 = W + o;      o += E1v;
    int* offs2 = (int*)(W + o); o += N2v;
    int* aux2 = (int*)(W + o);  o += 256;
    int* srcC2 = (int*)(W + o); o += E2v;
    float* normC2 = W + o;      o += E2v;
    float* h1P = W + o; size_t h1P_off = o; o += (size_t)N1v * 64;
    float* h1A = W + o; size_t h1A_off = o; o += (size_t)N1v * 64;
    // pack aliased onto h1P region (branch1 fully done before these are touched)
    size_t p = h1P_off;
    float* h2P = W + p;  p += (size_t)N2v * 64;
    float* h2A = W + p;  p += (size_t)N2v * 64;
    float* comb = W + p; p += PSZ;
    float* qkvb = W + p; p += (size_t)BRv * 192;
    float* obuf = W + p; p += PSZ;
    float* xbuf = W + p; p += PSZ;
    float* f1 = W + p;   p += PSZ;
    float* WinT = W + p; p += 64 * 192;
    float* WoutT = W + p; p += 64 * 64;
    // classifier partials aliased onto h1A (dead after branch-1 pooling): 128*64*1024 floats = 32MB
    float* Zp = W + h1A_off;

    dim3 blk(256);

    hipMemsetAsync(W, 0, zone_elems * sizeof(float), stream);

    // ===== branch 1 (node graph): CSR build =====
    k_deg_hist<<<E1v / 256, blk, 0, stream>>>(dst1, ew1, dinv1, counts1, E1v);
    k_dinv<<<N1v / 256, blk, 0, stream>>>(dinv1, N1v);
    k_scan1<<<N1v / 1024, blk, 0, stream>>>(counts1, offs1, aux1, N1v);
    k_scan2<<<1, blk, 0, stream>>>(aux1, N1v / 1024);
    k_scan3<<<N1v / 256, blk, 0, stream>>>(offs1, aux1, counts1, N1v);
    k_fill<<<E1v / 256, blk, 0, stream>>>(src1, dst1, ew1, dinv1, counts1, srcC1, normC1, E1v);
    // layers
    k_gemm_rowwave<1, false, false><<<4096, blk, 64 * 64 * 4, stream>>>(x_feat, Wg1, nullptr, h1P, N1v, 64);
    k_edge_gather<<<4096, blk, 0, stream>>>(srcC1, normC1, offs1, h1P, dinv1, bg1, h1A, N1v, E1v);
    k_gemm_rowwave<1, true, false><<<4096, blk, 64 * 64 * 4, stream>>>(h1A, Wg2, nullptr, h1P, N1v, 64);
    k_edge_gather<<<4096, blk, 0, stream>>>(srcC1, normC1, offs1, h1P, dinv1, bg2, h1A, N1v, E1v);
    k_pool_part<<<BBv * 4, blk, 0, stream>>>(h1A, node_roi, sums1, cnt1, N1v / BBv, 4);
    k_pool_fin<<<cdiv(PSZ, 256), blk, 0, stream>>>(sums1, cnt1, pooled_out, PSZ);

    // ===== branch 2 (roi graph): CSR build =====
    k_deg_hist<<<E2v / 256, blk, 0, stream>>>(dst2, ew2, dinv2, counts2, E2v);
    k_dinv<<<cdiv(N2v, 256), blk, 0, stream>>>(dinv2, N2v);
    k_scan1<<<cdiv(N2v, 1024), blk, 0, stream>>>(counts2, offs2, aux2, N2v);
    k_scan2<<<1, blk, 0, stream>>>(aux2, cdiv(N2v, 1024));
    k_scan3<<<cdiv(N2v, 256), blk, 0, stream>>>(offs2, aux2, counts2, N2v);
    k_fill<<<E2v / 256, blk, 0, stream>>>(src2, dst2, ew2, dinv2, counts2, srcC2, normC2, E2v);
    // layers
    k_gemm_rowwave<1, false, false><<<cdiv(N2v, 4), blk, 148 * 64 * 4, stream>>>(x2f, Wr1, nullptr, h2P, N2v, 148);
    k_edge_gather<<<cdiv(N2v, 4), blk, 0, stream>>>(srcC2, normC2, offs2, h2P, dinv2, br1, h2A, N2v, E2v);
    k_gemm_rowwave<1, true, false><<<cdiv(N2v, 4), blk, 64 * 64 * 4, stream>>>(h2A, Wr2, nullptr, h2P, N2v, 64);
    k_edge_gather<<<cdiv(N2v, 4), blk, 0, stream>>>(srcC2, normC2, offs2, h2P, dinv2, br2, h2A, N2v, E2v);
    k_pool_part<<<BBv, blk, 0, stream>>>(h2A, roi2, sums2, cnt2, RRv, 1);
    k_pool_fin2<<<cdiv(PSZ, 256), blk, 0, stream>>>(sums2, cnt2, pooled_out, pooledroi_out, comb, PSZ);

    // ===== transformer =====
    k_transpose<<<cdiv(192 * 64, 256), blk, 0, stream>>>(in_proj_w, WinT, 192, 64);
    k_transpose<<<cdiv(64 * 64, 256), blk, 0, stream>>>(out_proj_w, WoutT, 64, 64);
    k_gemm_rowwave<3, false, false><<<cdiv(N2v, 4), blk, 64 * 192 * 4, stream>>>(comb, WinT, in_proj_b, qkvb, N2v, 64);
    k_attn<<<BBv * 4, blk, 0, stream>>>(qkvb, attn_out, obuf);
    k_ln_gemm<<<cdiv(N2v, 4), blk, 0, stream>>>(obuf, WoutT, out_proj_b, comb, ln1_g, ln1_b, xbuf, N2v);
    k_gemm_rowwave<1, false, true><<<cdiv(N2v, 4), blk, 64 * 64 * 4, stream>>>(xbuf, ff_w1, ff_b1, f1, N2v, 64);
    k_ln_gemm<<<cdiv(N2v, 4), blk, 0, stream>>>(f1, ff_w2, ff_b2, xbuf, ln2_g, ln2_b, tout_out, N2v);

    // ===== classifier =====
    k_cls_part<<<512, blk, 0, stream>>>(tout_out, Wc1, Zp);
    k_cls_reduce<<<BBv * 1024 / 256, blk, 0, stream>>>(Zp, bc1, bn_g, bn_b, zbuf);
    k_cls_final<<<BBv, blk, 0, stream>>>(zbuf, Wc2, bc2, out);
}

// Round 4
// 931.060 us; speedup vs baseline: 1.6344x; 1.2680x over previous
//
#include <hip/hip_runtime.h>
#include <cstdint>
#include <cstddef>

#define N1v 262144
#define E1v 1048576
#define N2v 9472
#define E2v 262144
#define BBv 64
#define RRv 148
#define HIDv 1000
#define BRv (BBv * RRv)

static inline int cdiv(int a, int b) { return (a + b - 1) / b; }

typedef __attribute__((ext_vector_type(8))) short bf16x8;
typedef __attribute__((ext_vector_type(4))) float f32x4;

__device__ inline short f2bf(float f) {
    union { float f; unsigned u; } v; v.f = f;
    unsigned r = v.u + 0x7fff + ((v.u >> 16) & 1);   // RNE
    return (short)(r >> 16);
}

// ---------------- fused degree + histogram ----------------
__global__ __launch_bounds__(256) void k_deg_hist(const int* __restrict__ dst, const float* __restrict__ ew,
                                                  float* __restrict__ deg, int* __restrict__ counts, int E) {
    int i = blockIdx.x * 256 + threadIdx.x;
    if (i < E) {
        int d = dst[i];
        atomicAdd(&deg[d], ew[i]);
        atomicAdd(&counts[d], 1);
    }
}

__global__ __launch_bounds__(256) void k_dinv(float* __restrict__ deg, int N) {
    int i = blockIdx.x * 256 + threadIdx.x;
    if (i < N) deg[i] = rsqrtf(deg[i] + 1.0f);
}

// ---------------- 3-kernel exclusive scan (1024 elems/block) ----------------
__global__ __launch_bounds__(256) void k_scan1(const int* __restrict__ counts, int* __restrict__ offs,
                                               int* __restrict__ aux, int N) {
    __shared__ int tmp[256];
    int t = threadIdx.x;
    int base = blockIdx.x * 1024 + t * 4;
    int v0 = 0, v1 = 0, v2 = 0, v3 = 0;
    if (base + 3 < N) {
        int4 c = *(const int4*)(counts + base);
        v0 = c.x; v1 = c.y; v2 = c.z; v3 = c.w;
    } else {
        if (base < N) v0 = counts[base];
        if (base + 1 < N) v1 = counts[base + 1];
        if (base + 2 < N) v2 = counts[base + 2];
    }
    int tsum = v0 + v1 + v2 + v3;
    tmp[t] = tsum;
    __syncthreads();
    int val = tsum;
    for (int off = 1; off < 256; off <<= 1) {
        int other = (t >= off) ? tmp[t - off] : 0;
        __syncthreads();
        val += other;
        tmp[t] = val;
        __syncthreads();
    }
    int excl = val - tsum;
    if (base < N) offs[base] = excl;
    if (base + 1 < N) offs[base + 1] = excl + v0;
    if (base + 2 < N) offs[base + 2] = excl + v0 + v1;
    if (base + 3 < N) offs[base + 3] = excl + v0 + v1 + v2;
    if (t == 255) aux[blockIdx.x] = val;
}

__global__ __launch_bounds__(256) void k_scan2(int* __restrict__ aux, int nb) {
    __shared__ int tmp[256];
    int t = threadIdx.x;
    int v = (t < nb) ? aux[t] : 0;
    tmp[t] = v;
    __syncthreads();
    int val = v;
    for (int off = 1; off < 256; off <<= 1) {
        int other = (t >= off) ? tmp[t - off] : 0;
        __syncthreads();
        val += other;
        tmp[t] = val;
        __syncthreads();
    }
    if (t < nb) aux[t] = val - v;
}

__global__ __launch_bounds__(256) void k_scan3(int* __restrict__ offs, const int* __restrict__ aux,
                                               int* __restrict__ cursor, int N) {
    int i = blockIdx.x * 256 + threadIdx.x;
    if (i < N) {
        int val = offs[i] + aux[i >> 10];
        offs[i] = val;
        cursor[i] = val;
    }
}

// ---------------- CSR fill (+ fused sym-norm computation) ----------------
__global__ __launch_bounds__(256) void k_fill(const int* __restrict__ src, const int* __restrict__ dst,
                                              const float* __restrict__ ew, const float* __restrict__ dinv,
                                              int* __restrict__ cursor, int* __restrict__ srcC,
                                              float* __restrict__ normC, int E) {
    int e = blockIdx.x * 256 + threadIdx.x;
    if (e < E) {
        int s = src[e], d = dst[e];
        float nv = dinv[s] * ew[e] * dinv[d];
        int j = atomicAdd(&cursor[d], 1);
        srcC[j] = s;
        normC[j] = nv;
    }
}

// ---------------- edge gather: A[i] = sum_{e in csr[i]} P[src]*norm + P[i]*dinv^2 + b ----------------
__global__ __launch_bounds__(256) void k_edge_gather(const int* __restrict__ srcC, const float* __restrict__ normC,
                                                     const int* __restrict__ offs, const float* __restrict__ P,
                                                     const float* __restrict__ dinv, const float* __restrict__ bias,
                                                     float* __restrict__ A, int N, int E) {
    int lane = threadIdx.x & 63;
    int gw = blockIdx.x * 4 + (threadIdx.x >> 6);
    int tw = gridDim.x * 4;
    for (int i = gw; i < N; i += tw) {
        int beg = offs[i];
        int end = (i + 1 < N) ? offs[i + 1] : E;
        float di = dinv[i];
        float acc = fmaf(P[(size_t)i * 64 + lane], di * di, bias[lane]);
        for (int j = beg; j < end; ++j) {
            int s = srcC[j];
            float nv = normC[j];
            acc = fmaf(P[(size_t)s * 64 + lane], nv, acc);
        }
        A[(size_t)i * 64 + lane] = acc;
    }
}

// ---------------- MFMA bf16 GEMM: Y(N,64) = op(X)(N,64) @ W(64,64), fp32 in/out ----------------
// wave computes 16 rows x 64 cols; W held in registers as 8 B-frags.
template<bool RIN>
__global__ __launch_bounds__(256) void k_gemm_mfma(const float* __restrict__ X, const float* __restrict__ Wmat,
                                                   float* __restrict__ Y, int N) {
    int tid = threadIdx.x;
    int lane = tid & 63;
    int wv = tid >> 6;
    int l15 = lane & 15;
    int lg = lane >> 4;            // 0..3
    // B-frag: B[k][col], col = 16*ct + l15, k = 32*kh + 8*lg + i
    bf16x8 bfrag[2][4];
    for (int kh = 0; kh < 2; ++kh)
        for (int ct = 0; ct < 4; ++ct) {
            bf16x8 b;
#pragma unroll
            for (int i = 0; i < 8; ++i)
                b[i] = f2bf(Wmat[(size_t)(kh * 32 + lg * 8 + i) * 64 + ct * 16 + l15]);
            bfrag[kh][ct] = b;
        }
    int gw = blockIdx.x * 4 + wv;
    int tw = gridDim.x * 4;
    int ntiles = N >> 4;
    for (int t = gw; t < ntiles; t += tw) {
        int row0 = t << 4;
        // A-frag: A[row][k], row = row0 + l15, k = 8*lg + i  (+32 for kh=1)
        const float* xp = X + (size_t)(row0 + l15) * 64 + lg * 8;
        float4 a0 = *(const float4*)(xp);
        float4 a1 = *(const float4*)(xp + 4);
        float4 a2 = *(const float4*)(xp + 32);
        float4 a3 = *(const float4*)(xp + 36);
        if (RIN) {
            a0.x = fmaxf(a0.x, 0.f); a0.y = fmaxf(a0.y, 0.f); a0.z = fmaxf(a0.z, 0.f); a0.w = fmaxf(a0.w, 0.f);
            a1.x = fmaxf(a1.x, 0.f); a1.y = fmaxf(a1.y, 0.f); a1.z = fmaxf(a1.z, 0.f); a1.w = fmaxf(a1.w, 0.f);
            a2.x = fmaxf(a2.x, 0.f); a2.y = fmaxf(a2.y, 0.f); a2.z = fmaxf(a2.z, 0.f); a2.w = fmaxf(a2.w, 0.f);
            a3.x = fmaxf(a3.x, 0.f); a3.y = fmaxf(a3.y, 0.f); a3.z = fmaxf(a3.z, 0.f); a3.w = fmaxf(a3.w, 0.f);
        }
        bf16x8 af0, af1;
        af0[0] = f2bf(a0.x); af0[1] = f2bf(a0.y); af0[2] = f2bf(a0.z); af0[3] = f2bf(a0.w);
        af0[4] = f2bf(a1.x); af0[5] = f2bf(a1.y); af0[6] = f2bf(a1.z); af0[7] = f2bf(a1.w);
        af1[0] = f2bf(a2.x); af1[1] = f2bf(a2.y); af1[2] = f2bf(a2.z); af1[3] = f2bf(a2.w);
        af1[4] = f2bf(a3.x); af1[5] = f2bf(a3.y); af1[6] = f2bf(a3.z); af1[7] = f2bf(a3.w);
        f32x4 acc0 = {0.f, 0.f, 0.f, 0.f}, acc1 = acc0, acc2 = acc0, acc3 = acc0;
        acc0 = __builtin_amdgcn_mfma_f32_16x16x32_bf16(af0, bfrag[0][0], acc0, 0, 0, 0);
        acc1 = __builtin_amdgcn_mfma_f32_16x16x32_bf16(af0, bfrag[0][1], acc1, 0, 0, 0);
        acc2 = __builtin_amdgcn_mfma_f32_16x16x32_bf16(af0, bfrag[0][2], acc2, 0, 0, 0);
        acc3 = __builtin_amdgcn_mfma_f32_16x16x32_bf16(af0, bfrag[0][3], acc3, 0, 0, 0);
        acc0 = __builtin_amdgcn_mfma_f32_16x16x32_bf16(af1, bfrag[1][0], acc0, 0, 0, 0);
        acc1 = __builtin_amdgcn_mfma_f32_16x16x32_bf16(af1, bfrag[1][1], acc1, 0, 0, 0);
        acc2 = __builtin_amdgcn_mfma_f32_16x16x32_bf16(af1, bfrag[1][2], acc2, 0, 0, 0);
        acc3 = __builtin_amdgcn_mfma_f32_16x16x32_bf16(af1, bfrag[1][3], acc3, 0, 0, 0);
        // C/D: row = row0 + 4*lg + r, col = 16*ct + l15
        float* yp = Y + (size_t)(row0 + lg * 4) * 64 + l15;
#pragma unroll
        for (int r = 0; r < 4; ++r) {
            yp[(size_t)r * 64 + 0]  = acc0[r];
            yp[(size_t)r * 64 + 16] = acc1[r];
            yp[(size_t)r * 64 + 32] = acc2[r];
            yp[(size_t)r * 64 + 48] = acc3[r];
        }
    }
}

// ---------------- row-per-wave GEMM (small N paths): Y = op(X) @ W [+bias][relu] ----------------
template<int MB, bool RIN, bool ROUT>
__global__ __launch_bounds__(256) void k_gemm_rowwave(const float* __restrict__ X, const float* __restrict__ W,
                                                      const float* __restrict__ bias, float* __restrict__ Y,
                                                      int N, int K) {
    extern __shared__ float Wl[];
    const int M = MB * 64;
    for (int idx = threadIdx.x; idx < K * M; idx += 256) Wl[idx] = W[idx];
    __syncthreads();
    int lane = threadIdx.x & 63;
    int gw = blockIdx.x * 4 + (threadIdx.x >> 6);
    int tw = gridDim.x * 4;
    const int K4 = K >> 2;
    for (int row = gw; row < N; row += tw) {
        float acc[MB];
#pragma unroll
        for (int cb = 0; cb < MB; ++cb) acc[cb] = 0.f;
        const float4* xr = (const float4*)(X + (size_t)row * K);
        for (int k4 = 0; k4 < K4; ++k4) {
            float4 xv = xr[k4];
            if (RIN) {
                xv.x = fmaxf(xv.x, 0.f); xv.y = fmaxf(xv.y, 0.f);
                xv.z = fmaxf(xv.z, 0.f); xv.w = fmaxf(xv.w, 0.f);
            }
            const float* wp = Wl + (k4 * 4) * M + lane;
#pragma unroll
            for (int cb = 0; cb < MB; ++cb) acc[cb] = fmaf(xv.x, wp[cb * 64], acc[cb]);
            wp += M;
#pragma unroll
            for (int cb = 0; cb < MB; ++cb) acc[cb] = fmaf(xv.y, wp[cb * 64], acc[cb]);
            wp += M;
#pragma unroll
            for (int cb = 0; cb < MB; ++cb) acc[cb] = fmaf(xv.z, wp[cb * 64], acc[cb]);
            wp += M;
#pragma unroll
            for (int cb = 0; cb < MB; ++cb) acc[cb] = fmaf(xv.w, wp[cb * 64], acc[cb]);
        }
#pragma unroll
        for (int cb = 0; cb < MB; ++cb) {
            float y = acc[cb];
            int col = cb * 64 + lane;
            if (bias) y += bias[col];
            if (ROUT) y = fmaxf(y, 0.f);
            Y[(size_t)row * M + col] = y;
        }
    }
}

// ---------------- ROI pool partials: LDS accumulate per (graph, part), merge to global ----------------
__global__ __launch_bounds__(256) void k_pool_part(const float* __restrict__ A, const int* __restrict__ roi,
                                                   float* __restrict__ sums, float* __restrict__ cnt,
                                                   int npg, int bpg) {
    int b = blockIdx.x / bpg;
    int part = blockIdx.x - b * bpg;
    __shared__ float ls[RRv * 64];
    __shared__ int lc[RRv];
    int tid = threadIdx.x;
    for (int idx = tid; idx < RRv * 64; idx += 256) ls[idx] = 0.f;
    for (int idx = tid; idx < RRv; idx += 256) lc[idx] = 0;
    __syncthreads();
    int wv = tid >> 6, lane = tid & 63;
    int wig = part * 4 + wv, stride = bpg * 4;
    for (int i = wig; i < npg; i += stride) {
        int node = b * npg + i;
        int r = roi[node];
        atomicAdd(&ls[r * 64 + lane], fmaxf(A[(size_t)node * 64 + lane], 0.f));
        if (lane == 0) atomicAdd(&lc[r], 1);
    }
    __syncthreads();
    float* sb = sums + (size_t)b * RRv * 64;
    for (int idx = tid; idx < RRv * 64; idx += 256) {
        float v = ls[idx];
        if (v != 0.f) atomicAdd(&sb[idx], v);
    }
    for (int idx = tid; idx < RRv; idx += 256) {
        int c = lc[idx];
        if (c) atomicAdd(&cnt[b * RRv + idx], (float)c);
    }
}

__global__ __launch_bounds__(256) void k_pool_fin(const float* __restrict__ sums, const float* __restrict__ cnt,
                                                  float* __restrict__ outp, int total) {
    int i = blockIdx.x * 256 + threadIdx.x;
    if (i < total) outp[i] = sums[i] / fmaxf(cnt[i >> 6], 1.f);
}

// fin for branch2: also emits comb = pooled_roi + pooled
__global__ __launch_bounds__(256) void k_pool_fin2(const float* __restrict__ sums, const float* __restrict__ cnt,
                                                   const float* __restrict__ other, float* __restrict__ outp,
                                                   float* __restrict__ comb, int total) {
    int i = blockIdx.x * 256 + threadIdx.x;
    if (i < total) {
        float v = sums[i] / fmaxf(cnt[i >> 6], 1.f);
        outp[i] = v;
        comb[i] = v + other[i];
    }
}

// ---------------- transpose W(rows,cols) -> Wt(cols,rows) ----------------
__global__ __launch_bounds__(256) void k_transpose(const float* __restrict__ W, float* __restrict__ Wt,
                                                   int rows, int cols) {
    int i = blockIdx.x * 256 + threadIdx.x;
    if (i < rows * cols) {
        int r = i / cols, c = i - r * cols;
        Wt[c * rows + r] = W[i];
    }
}

// ---------------- attention: one block per (b,h) ----------------
__global__ __launch_bounds__(256) void k_attn(const float* __restrict__ qkv, float* __restrict__ aw,
                                              float* __restrict__ o) {
    int bh = blockIdx.x;
    int b = bh >> 2, h = bh & 3;
    __shared__ float qs[148][16];
    __shared__ float kT[16][152];
    __shared__ float vs[148][16];
    __shared__ float ps[4][152];
    int tid = threadIdx.x;
    const float* base = qkv + (size_t)b * 148 * 192 + h * 16;
    for (int idx = tid; idx < 148 * 16; idx += 256) {
        int i = idx >> 4, d = idx & 15;
        const float* p = base + (size_t)i * 192 + d;
        qs[i][d] = p[0] * 0.25f;
        kT[d][i] = p[64];
        vs[i][d] = p[128];
    }
    __syncthreads();
    int wv = tid >> 6, lane = tid & 63;
    float* aw_bh = aw + (size_t)bh * 148 * 148;
    for (int i = wv; i < 148; i += 4) {
        float s0 = 0.f, s1 = 0.f, s2 = 0.f;
#pragma unroll
        for (int d = 0; d < 16; ++d) {
            float q = qs[i][d];
            s0 = fmaf(q, kT[d][lane], s0);
            s1 = fmaf(q, kT[d][lane + 64], s1);
            if (lane < 20) s2 = fmaf(q, kT[d][lane + 128], s2);
        }
        float m = fmaxf(s0, s1);
        if (lane < 20) m = fmaxf(m, s2);
#pragma unroll
        for (int off = 1; off < 64; off <<= 1) m = fmaxf(m, __shfl_xor(m, off));
        float e0 = __expf(s0 - m), e1 = __expf(s1 - m);
        float e2 = (lane < 20) ? __expf(s2 - m) : 0.f;
        float sum = e0 + e1 + e2;
#pragma unroll
        for (int off = 1; off < 64; off <<= 1) sum += __shfl_xor(sum, off);
        float inv = 1.f / sum;
        float p0 = e0 * inv, p1 = e1 * inv, p2 = e2 * inv;
        float* awr = aw_bh + (size_t)i * 148;
        awr[lane] = p0;
        awr[lane + 64] = p1;
        if (lane < 20) awr[lane + 128] = p2;
        ps[wv][lane] = p0;
        ps[wv][lane + 64] = p1;
        if (lane < 20) ps[wv][lane + 128] = p2;
        int d = lane & 15, jj = lane >> 4;
        float acc = 0.f;
        for (int t = jj; t < 148; t += 4) acc = fmaf(ps[wv][t], vs[t][d], acc);
        acc += __shfl_xor(acc, 16);
        acc += __shfl_xor(acc, 32);
        if (lane < 16) o[((size_t)b * 148 + i) * 64 + h * 16 + d] = acc;
    }
}

// ---------------- fused GEMM + bias + residual + LayerNorm (K=M=64) ----------------
__global__ __launch_bounds__(256) void k_ln_gemm(const float* __restrict__ X, const float* __restrict__ Wt,
                                                 const float* __restrict__ bias, const float* __restrict__ resid,
                                                 const float* __restrict__ g, const float* __restrict__ bb,
                                                 float* __restrict__ Y, int N) {
    __shared__ float Wl[4096];
    for (int idx = threadIdx.x; idx < 4096; idx += 256) Wl[idx] = Wt[idx];
    __syncthreads();
    int lane = threadIdx.x & 63;
    int gw = blockIdx.x * 4 + (threadIdx.x >> 6);
    int tw = gridDim.x * 4;
    for (int row = gw; row < N; row += tw) {
        const float4* xr = (const float4*)(X + (size_t)row * 64);
        float acc = 0.f;
        for (int k4 = 0; k4 < 16; ++k4) {
            float4 xv = xr[k4];
            const float* wp = Wl + (k4 * 4) * 64 + lane;
            acc = fmaf(xv.x, wp[0], acc);
            acc = fmaf(xv.y, wp[64], acc);
            acc = fmaf(xv.z, wp[128], acc);
            acc = fmaf(xv.w, wp[192], acc);
        }
        float y = acc + bias[lane] + resid[(size_t)row * 64 + lane];
        float s = y;
#pragma unroll
        for (int off = 1; off < 64; off <<= 1) s += __shfl_xor(s, off);
        float mu = s * (1.f / 64.f);
        float dcen = y - mu;
        float v = dcen * dcen;
#pragma unroll
        for (int off = 1; off < 64; off <<= 1) v += __shfl_xor(v, off);
        float var = v * (1.f / 64.f);
        Y[(size_t)row * 64 + lane] = dcen * rsqrtf(var + 1e-5f) * g[lane] + bb[lane];
    }
}

// ---------------- classifier stage A: partial GEMM, no atomics ----------------
__global__ __launch_bounds__(256) void k_cls_part(const float* __restrict__ T, const float* __restrict__ Wc1,
                                                  float* __restrict__ Zp) {
    int ks = blockIdx.x >> 2;
    int mt = blockIdx.x & 3;
    int k0 = ks * 74;
    int m0 = mt * 256;
    __shared__ float Tl[64][74];
    int tid = threadIdx.x;
    for (int idx = tid; idx < 64 * 74; idx += 256) {
        int b = idx / 74, kk = idx - b * 74;
        Tl[b][kk] = T[(size_t)b * 9472 + k0 + kk];
    }
    __syncthreads();
    int lane = tid & 63, bq = tid >> 6;
    int mbase = m0 + lane * 4;
    size_t moff = (mbase + 3 < 1000) ? (size_t)mbase : 0;
    float4 acc[16];
#pragma unroll
    for (int j = 0; j < 16; ++j) acc[j] = make_float4(0.f, 0.f, 0.f, 0.f);
#pragma unroll 2
    for (int kk = 0; kk < 74; ++kk) {
        float4 w = *(const float4*)(Wc1 + (size_t)(k0 + kk) * 1000 + moff);
#pragma unroll
        for (int j = 0; j < 16; ++j) {
            float t = Tl[bq * 16 + j][kk];
            acc[j].x = fmaf(t, w.x, acc[j].x);
            acc[j].y = fmaf(t, w.y, acc[j].y);
            acc[j].z = fmaf(t, w.z, acc[j].z);
            acc[j].w = fmaf(t, w.w, acc[j].w);
        }
    }
    float* zp = Zp + (size_t)ks * 64 * 1024;
#pragma unroll
    for (int j = 0; j < 16; ++j) {
        int b = bq * 16 + j;
        *(float4*)(zp + (size_t)b * 1024 + mbase) = acc[j];
    }
}

// ---------------- classifier stage B: reduce partials + bias + BN + leaky ----------------
__global__ __launch_bounds__(256) void k_cls_reduce(const float* __restrict__ Zp, const float* __restrict__ bc1,
                                                    const float* __restrict__ bn_g, const float* __restrict__ bn_b,
                                                    float* __restrict__ zb) {
    int flat = blockIdx.x * 256 + threadIdx.x;
    int b = flat >> 10, m = flat & 1023;
    if (m >= 1000) return;
    float s = 0.f;
    for (int ks = 0; ks < 128; ++ks)
        s += Zp[((size_t)ks * 64 + b) * 1024 + m];
    float rs = rsqrtf(1.0f + 1e-5f);
    float z = bn_g[m] * (s + bc1[m]) * rs + bn_b[m];
    zb[flat] = z >= 0.f ? z : 0.01f * z;
}

// ---------------- classifier finish: 1000 -> 2 matvec ----------------
__global__ __launch_bounds__(256) void k_cls_final(const float* __restrict__ zb,
                                                   const float* __restrict__ Wc2, const float* __restrict__ bc2,
                                                   float* __restrict__ out) {
    int b = blockIdx.x;
    int tid = threadIdx.x;
    float a0 = 0.f, a1 = 0.f;
    for (int m = tid; m < 1000; m += 256) {
        float z = zb[b * 1024 + m];
        a0 = fmaf(z, Wc2[m * 2], a0);
        a1 = fmaf(z, Wc2[m * 2 + 1], a1);
    }
#pragma unroll
    for (int off = 1; off < 64; off <<= 1) {
        a0 += __shfl_xor(a0, off);
        a1 += __shfl_xor(a1, off);
    }
    __shared__ float r0[4], r1[4];
    if ((tid & 63) == 0) { r0[tid >> 6] = a0; r1[tid >> 6] = a1; }
    __syncthreads();
    if (tid == 0) {
        out[b * 2 + 0] = r0[0] + r0[1] + r0[2] + r0[3] + bc2[0];
        out[b * 2 + 1] = r1[0] + r1[1] + r1[2] + r1[3] + bc2[1];
    }
}

extern "C" void kernel_launch(void* const* d_in, const int* in_sizes, int n_in,
                              void* d_out, int out_size, void* d_ws, size_t ws_size,
                              hipStream_t stream) {
    (void)in_sizes; (void)n_in; (void)out_size; (void)ws_size;

    const float* x_feat = (const float*)d_in[0];
    const int* node_roi = (const int*)d_in[1];
    const int* ei1 = (const int*)d_in[3];
    const float* ew1 = (const float*)d_in[4];
    const float* x2f = (const float*)d_in[5];
    const int* roi2 = (const int*)d_in[6];
    const int* ei2 = (const int*)d_in[8];
    const float* ew2 = (const float*)d_in[9];
    const float* Wg1 = (const float*)d_in[10];
    const float* bg1 = (const float*)d_in[11];
    const float* Wg2 = (const float*)d_in[12];
    const float* bg2 = (const float*)d_in[13];
    const float* Wr1 = (const float*)d_in[14];
    const float* br1 = (const float*)d_in[15];
    const float* Wr2 = (const float*)d_in[16];
    const float* br2 = (const float*)d_in[17];
    const float* in_proj_w = (const float*)d_in[18];
    const float* in_proj_b = (const float*)d_in[19];
    const float* out_proj_w = (const float*)d_in[20];
    const float* out_proj_b = (const float*)d_in[21];
    const float* ln1_g = (const float*)d_in[22];
    const float* ln1_b = (const float*)d_in[23];
    const float* ff_w1 = (const float*)d_in[24];
    const float* ff_b1 = (const float*)d_in[25];
    const float* ff_w2 = (const float*)d_in[26];
    const float* ff_b2 = (const float*)d_in[27];
    const float* ln2_g = (const float*)d_in[28];
    const float* ln2_b = (const float*)d_in[29];
    const float* Wc1 = (const float*)d_in[30];
    const float* bc1 = (const float*)d_in[31];
    const float* bn_g = (const float*)d_in[32];
    const float* bn_b = (const float*)d_in[33];
    const float* Wc2 = (const float*)d_in[34];
    const float* bc2 = (const float*)d_in[35];

    const int* src1 = ei1;
    const int* dst1 = ei1 + E1v;
    const int* src2 = ei2;
    const int* dst2 = ei2 + E2v;

    float* out = (float*)d_out;
    const int PSZ = BRv * 64;
    float* pooled_out = out + 128;
    float* pooledroi_out = out + 128 + PSZ;
    float* tout_out = out + 128 + 2 * PSZ;
    float* attn_out = out + 128 + 3 * PSZ;

    // ===== workspace layout (floats) =====
    float* W = (float*)d_ws;
    size_t o = 0;
    float* dinv1 = W + o;       o += N1v;
    int* counts1 = (int*)(W + o); o += N1v;
    float* dinv2 = W + o;       o += N2v;
    int* counts2 = (int*)(W + o); o += N2v;
    float* sums1 = W + o;       o += PSZ;
    float* cnt1 = W + o;        o += BRv;
    float* sums2 = W + o;       o += PSZ;
    float* cnt2 = W + o;        o += BRv;
    float* zbuf = W + o;        o += BBv * 1024;
    size_t zone_elems = o;
    int* offs1 = (int*)(W + o); o += N1v;
    int* aux1 = (int*)(W + o);  o += 256;
    int* srcC1 = (int*)(W + o); o += E1v;
    float* normC1 = W + o;      o += E1v;
    int* offs2 = (int*)(W + o); o += N2v;
    int* aux2 = (int*)(W + o);  o += 256;
    int* srcC2 = (int*)(W + o); o += E2v;
    float* normC2 = W + o;      o += E2v;
    float* h1P = W + o; size_t h1P_off = o; o += (size_t)N1v * 64;
    float* h1A = W + o; size_t h1A_off = o; o += (size_t)N1v * 64;
    size_t p = h1P_off;
    float* h2P = W + p;  p += (size_t)N2v * 64;
    float* h2A = W + p;  p += (size_t)N2v * 64;
    float* comb = W + p; p += PSZ;
    float* qkvb = W + p; p += (size_t)BRv * 192;
    float* obuf = W + p; p += PSZ;
    float* xbuf = W + p; p += PSZ;
    float* f1 = W + p;   p += PSZ;
    float* WinT = W + p; p += 64 * 192;
    float* WoutT = W + p; p += 64 * 64;
    float* Zp = W + h1A_off;   // 128*64*1024 floats, aliased onto dead h1A

    dim3 blk(256);

    hipMemsetAsync(W, 0, zone_elems * sizeof(float), stream);

    // ===== branch 1 (node graph): CSR build =====
    k_deg_hist<<<E1v / 256, blk, 0, stream>>>(dst1, ew1, dinv1, counts1, E1v);
    k_dinv<<<N1v / 256, blk, 0, stream>>>(dinv1, N1v);
    k_scan1<<<N1v / 1024, blk, 0, stream>>>(counts1, offs1, aux1, N1v);
    k_scan2<<<1, blk, 0, stream>>>(aux1, N1v / 1024);
    k_scan3<<<N1v / 256, blk, 0, stream>>>(offs1, aux1, counts1, N1v);
    k_fill<<<E1v / 256, blk, 0, stream>>>(src1, dst1, ew1, dinv1, counts1, srcC1, normC1, E1v);
    // layers (MFMA bf16 GEMMs)
    k_gemm_mfma<false><<<2048, blk, 0, stream>>>(x_feat, Wg1, h1P, N1v);
    k_edge_gather<<<4096, blk, 0, stream>>>(srcC1, normC1, offs1, h1P, dinv1, bg1, h1A, N1v, E1v);
    k_gemm_mfma<true><<<2048, blk, 0, stream>>>(h1A, Wg2, h1P, N1v);
    k_edge_gather<<<4096, blk, 0, stream>>>(srcC1, normC1, offs1, h1P, dinv1, bg2, h1A, N1v, E1v);
    k_pool_part<<<BBv * 4, blk, 0, stream>>>(h1A, node_roi, sums1, cnt1, N1v / BBv, 4);
    k_pool_fin<<<cdiv(PSZ, 256), blk, 0, stream>>>(sums1, cnt1, pooled_out, PSZ);

    // ===== branch 2 (roi graph): CSR build =====
    k_deg_hist<<<E2v / 256, blk, 0, stream>>>(dst2, ew2, dinv2, counts2, E2v);
    k_dinv<<<cdiv(N2v, 256), blk, 0, stream>>>(dinv2, N2v);
    k_scan1<<<cdiv(N2v, 1024), blk, 0, stream>>>(counts2, offs2, aux2, N2v);
    k_scan2<<<1, blk, 0, stream>>>(aux2, cdiv(N2v, 1024));
    k_scan3<<<cdiv(N2v, 256), blk, 0, stream>>>(offs2, aux2, counts2, N2v);
    k_fill<<<E2v / 256, blk, 0, stream>>>(src2, dst2, ew2, dinv2, counts2, srcC2, normC2, E2v);
    // layers
    k_gemm_rowwave<1, false, false><<<cdiv(N2v, 4), blk, 148 * 64 * 4, stream>>>(x2f, Wr1, nullptr, h2P, N2v, 148);
    k_edge_gather<<<cdiv(N2v, 4), blk, 0, stream>>>(srcC2, normC2, offs2, h2P, dinv2, br1, h2A, N2v, E2v);
    k_gemm_rowwave<1, true, false><<<cdiv(N2v, 4), blk, 64 * 64 * 4, stream>>>(h2A, Wr2, nullptr, h2P, N2v, 64);
    k_edge_gather<<<cdiv(N2v, 4), blk, 0, stream>>>(srcC2, normC2, offs2, h2P, dinv2, br2, h2A, N2v, E2v);
    k_pool_part<<<BBv, blk, 0, stream>>>(h2A, roi2, sums2, cnt2, RRv, 1);
    k_pool_fin2<<<cdiv(PSZ, 256), blk, 0, stream>>>(sums2, cnt2, pooled_out, pooledroi_out, comb, PSZ);

    // ===== transformer =====
    k_transpose<<<cdiv(192 * 64, 256), blk, 0, stream>>>(in_proj_w, WinT, 192, 64);
    k_transpose<<<cdiv(64 * 64, 256), blk, 0, stream>>>(out_proj_w, WoutT, 64, 64);
    k_gemm_rowwave<3, false, false><<<cdiv(N2v, 4), blk, 64 * 192 * 4, stream>>>(comb, WinT, in_proj_b, qkvb, N2v, 64);
    k_attn<<<BBv * 4, blk, 0, stream>>>(qkvb, attn_out, obuf);
    k_ln_gemm<<<cdiv(N2v, 4), blk, 0, stream>>>(obuf, WoutT, out_proj_b, comb, ln1_g, ln1_b, xbuf, N2v);
    k_gemm_rowwave<1, false, true><<<cdiv(N2v, 4), blk, 64 * 64 * 4, stream>>>(xbuf, ff_w1, ff_b1, f1, N2v, 64);
    k_ln_gemm<<<cdiv(N2v, 4), blk, 0, stream>>>(f1, ff_w2, ff_b2, xbuf, ln2_g, ln2_b, tout_out, N2v);

    // ===== classifier =====
    k_cls_part<<<512, blk, 0, stream>>>(tout_out, Wc1, Zp);
    k_cls_reduce<<<BBv * 1024 / 256, blk, 0, stream>>>(Zp, bc1, bn_g, bn_b, zbuf);
    k_cls_final<<<BBv, blk, 0, stream>>>(zbuf, Wc2, bc2, out);
}

// Round 5
// 793.761 us; speedup vs baseline: 1.9171x; 1.1730x over previous
//
#include <hip/hip_runtime.h>
#include <cstdint>
#include <cstddef>

#define N1v 262144
#define E1v 1048576
#define N2v 9472
#define E2v 262144
#define BBv 64
#define RRv 148
#define HIDv 1000
#define BRv (BBv * RRv)

static inline int cdiv(int a, int b) { return (a + b - 1) / b; }

typedef __attribute__((ext_vector_type(8))) short bf16x8;
typedef __attribute__((ext_vector_type(4))) float f32x4;
typedef unsigned short ushort_t;

__device__ inline short f2bf(float f) {
    union { float f; unsigned u; } v; v.f = f;
    unsigned r = v.u + 0x7fff + ((v.u >> 16) & 1);   // RNE
    return (short)(r >> 16);
}
__device__ inline float bf2f(unsigned hs) {
    union { unsigned u; float f; } v; v.u = hs << 16; return v.f;
}

// ---------------- fused degree + histogram ----------------
__global__ __launch_bounds__(256) void k_deg_hist(const int* __restrict__ dst, const float* __restrict__ ew,
                                                  float* __restrict__ deg, int* __restrict__ counts, int E) {
    int i = blockIdx.x * 256 + threadIdx.x;
    if (i < E) {
        int d = dst[i];
        atomicAdd(&deg[d], ew[i]);
        atomicAdd(&counts[d], 1);
    }
}

__global__ __launch_bounds__(256) void k_dinv(float* __restrict__ deg, int N) {
    int i = blockIdx.x * 256 + threadIdx.x;
    if (i < N) deg[i] = rsqrtf(deg[i] + 1.0f);
}

// ---------------- 3-kernel exclusive scan (1024 elems/block) ----------------
__global__ __launch_bounds__(256) void k_scan1(const int* __restrict__ counts, int* __restrict__ offs,
                                               int* __restrict__ aux, int N) {
    __shared__ int tmp[256];
    int t = threadIdx.x;
    int base = blockIdx.x * 1024 + t * 4;
    int v0 = 0, v1 = 0, v2 = 0, v3 = 0;
    if (base + 3 < N) {
        int4 c = *(const int4*)(counts + base);
        v0 = c.x; v1 = c.y; v2 = c.z; v3 = c.w;
    } else {
        if (base < N) v0 = counts[base];
        if (base + 1 < N) v1 = counts[base + 1];
        if (base + 2 < N) v2 = counts[base + 2];
    }
    int tsum = v0 + v1 + v2 + v3;
    tmp[t] = tsum;
    __syncthreads();
    int val = tsum;
    for (int off = 1; off < 256; off <<= 1) {
        int other = (t >= off) ? tmp[t - off] : 0;
        __syncthreads();
        val += other;
        tmp[t] = val;
        __syncthreads();
    }
    int excl = val - tsum;
    if (base < N) offs[base] = excl;
    if (base + 1 < N) offs[base + 1] = excl + v0;
    if (base + 2 < N) offs[base + 2] = excl + v0 + v1;
    if (base + 3 < N) offs[base + 3] = excl + v0 + v1 + v2;
    if (t == 255) aux[blockIdx.x] = val;
}

__global__ __launch_bounds__(256) void k_scan2(int* __restrict__ aux, int nb) {
    __shared__ int tmp[256];
    int t = threadIdx.x;
    int v = (t < nb) ? aux[t] : 0;
    tmp[t] = v;
    __syncthreads();
    int val = v;
    for (int off = 1; off < 256; off <<= 1) {
        int other = (t >= off) ? tmp[t - off] : 0;
        __syncthreads();
        val += other;
        tmp[t] = val;
        __syncthreads();
    }
    if (t < nb) aux[t] = val - v;
}

__global__ __launch_bounds__(256) void k_scan3(int* __restrict__ offs, const int* __restrict__ aux,
                                               int* __restrict__ cursor, int N) {
    int i = blockIdx.x * 256 + threadIdx.x;
    if (i < N) {
        int val = offs[i] + aux[i >> 10];
        offs[i] = val;
        cursor[i] = val;
    }
}

// ---------------- CSR fill (+ fused sym-norm computation) ----------------
__global__ __launch_bounds__(256) void k_fill(const int* __restrict__ src, const int* __restrict__ dst,
                                              const float* __restrict__ ew, const float* __restrict__ dinv,
                                              int* __restrict__ cursor, int* __restrict__ srcC,
                                              float* __restrict__ normC, int E) {
    int e = blockIdx.x * 256 + threadIdx.x;
    if (e < E) {
        int s = src[e], d = dst[e];
        float nv = dinv[s] * ew[e] * dinv[d];
        int j = atomicAdd(&cursor[d], 1);
        srcC[j] = s;
        normC[j] = nv;
    }
}

// ---------------- edge gather v2: 4 edge-slots x 16 lanes, bf16 P rows ----------------
// A[i] = sum_e P[src_e]*norm_e + P[i]*dinv^2 + b   (A fp32, P bf16)
__global__ __launch_bounds__(256) void k_edge_gather2(const int* __restrict__ srcC, const float* __restrict__ normC,
                                                      const int* __restrict__ offs, const ushort_t* __restrict__ Pb,
                                                      const float* __restrict__ dinv, const float* __restrict__ bias,
                                                      float* __restrict__ A, int N, int E) {
    int tid = threadIdx.x;
    int lane = tid & 63;
    int es = lane >> 4;        // edge slot 0..3
    int fq = lane & 15;        // feature quarter (4 floats)
    float4 bv = *(const float4*)(bias + fq * 4);
    int gw = blockIdx.x * 4 + (tid >> 6);
    int tw = gridDim.x * 4;
    for (int i = gw; i < N; i += tw) {
        int beg = offs[i];
        int end = (i + 1 < N) ? offs[i + 1] : E;
        float ax = 0.f, ay = 0.f, az = 0.f, aw = 0.f;
        for (int j = beg + es; j < end; j += 4) {
            int s = srcC[j];
            float nv = normC[j];
            uint2 w = *(const uint2*)(Pb + (size_t)s * 64 + fq * 4);
            ax = fmaf(nv, bf2f(w.x & 0xffffu), ax);
            ay = fmaf(nv, bf2f(w.x >> 16), ay);
            az = fmaf(nv, bf2f(w.y & 0xffffu), az);
            aw = fmaf(nv, bf2f(w.y >> 16), aw);
        }
        ax += __shfl_xor(ax, 16); ay += __shfl_xor(ay, 16);
        az += __shfl_xor(az, 16); aw += __shfl_xor(aw, 16);
        ax += __shfl_xor(ax, 32); ay += __shfl_xor(ay, 32);
        az += __shfl_xor(az, 32); aw += __shfl_xor(aw, 32);
        if (es == 0) {
            float di = dinv[i];
            float s2 = di * di;
            uint2 w = *(const uint2*)(Pb + (size_t)i * 64 + fq * 4);
            float4 r;
            r.x = fmaf(s2, bf2f(w.x & 0xffffu), ax) + bv.x;
            r.y = fmaf(s2, bf2f(w.x >> 16), ay) + bv.y;
            r.z = fmaf(s2, bf2f(w.y & 0xffffu), az) + bv.z;
            r.w = fmaf(s2, bf2f(w.y >> 16), aw) + bv.w;
            *(float4*)(A + (size_t)i * 64 + fq * 4) = r;
        }
    }
}

// ---------------- MFMA bf16 GEMM: Yb(N,64) = bf16( op(X)(N,64) @ W(64,64) ) ----------------
template<bool RIN>
__global__ __launch_bounds__(256) void k_gemm_mfma(const float* __restrict__ X, const float* __restrict__ Wmat,
                                                   ushort_t* __restrict__ Y, int N) {
    int tid = threadIdx.x;
    int lane = tid & 63;
    int wv = tid >> 6;
    int l15 = lane & 15;
    int lg = lane >> 4;
    bf16x8 bfrag[2][4];
    for (int kh = 0; kh < 2; ++kh)
        for (int ct = 0; ct < 4; ++ct) {
            bf16x8 b;
#pragma unroll
            for (int i = 0; i < 8; ++i)
                b[i] = f2bf(Wmat[(size_t)(kh * 32 + lg * 8 + i) * 64 + ct * 16 + l15]);
            bfrag[kh][ct] = b;
        }
    int gw = blockIdx.x * 4 + wv;
    int tw = gridDim.x * 4;
    int ntiles = N >> 4;
    for (int t = gw; t < ntiles; t += tw) {
        int row0 = t << 4;
        const float* xp = X + (size_t)(row0 + l15) * 64 + lg * 8;
        float4 a0 = *(const float4*)(xp);
        float4 a1 = *(const float4*)(xp + 4);
        float4 a2 = *(const float4*)(xp + 32);
        float4 a3 = *(const float4*)(xp + 36);
        if (RIN) {
            a0.x = fmaxf(a0.x, 0.f); a0.y = fmaxf(a0.y, 0.f); a0.z = fmaxf(a0.z, 0.f); a0.w = fmaxf(a0.w, 0.f);
            a1.x = fmaxf(a1.x, 0.f); a1.y = fmaxf(a1.y, 0.f); a1.z = fmaxf(a1.z, 0.f); a1.w = fmaxf(a1.w, 0.f);
            a2.x = fmaxf(a2.x, 0.f); a2.y = fmaxf(a2.y, 0.f); a2.z = fmaxf(a2.z, 0.f); a2.w = fmaxf(a2.w, 0.f);
            a3.x = fmaxf(a3.x, 0.f); a3.y = fmaxf(a3.y, 0.f); a3.z = fmaxf(a3.z, 0.f); a3.w = fmaxf(a3.w, 0.f);
        }
        bf16x8 af0, af1;
        af0[0] = f2bf(a0.x); af0[1] = f2bf(a0.y); af0[2] = f2bf(a0.z); af0[3] = f2bf(a0.w);
        af0[4] = f2bf(a1.x); af0[5] = f2bf(a1.y); af0[6] = f2bf(a1.z); af0[7] = f2bf(a1.w);
        af1[0] = f2bf(a2.x); af1[1] = f2bf(a2.y); af1[2] = f2bf(a2.z); af1[3] = f2bf(a2.w);
        af1[4] = f2bf(a3.x); af1[5] = f2bf(a3.y); af1[6] = f2bf(a3.z); af1[7] = f2bf(a3.w);
        f32x4 acc0 = {0.f, 0.f, 0.f, 0.f}, acc1 = acc0, acc2 = acc0, acc3 = acc0;
        acc0 = __builtin_amdgcn_mfma_f32_16x16x32_bf16(af0, bfrag[0][0], acc0, 0, 0, 0);
        acc1 = __builtin_amdgcn_mfma_f32_16x16x32_bf16(af0, bfrag[0][1], acc1, 0, 0, 0);
        acc2 = __builtin_amdgcn_mfma_f32_16x16x32_bf16(af0, bfrag[0][2], acc2, 0, 0, 0);
        acc3 = __builtin_amdgcn_mfma_f32_16x16x32_bf16(af0, bfrag[0][3], acc3, 0, 0, 0);
        acc0 = __builtin_amdgcn_mfma_f32_16x16x32_bf16(af1, bfrag[1][0], acc0, 0, 0, 0);
        acc1 = __builtin_amdgcn_mfma_f32_16x16x32_bf16(af1, bfrag[1][1], acc1, 0, 0, 0);
        acc2 = __builtin_amdgcn_mfma_f32_16x16x32_bf16(af1, bfrag[1][2], acc2, 0, 0, 0);
        acc3 = __builtin_amdgcn_mfma_f32_16x16x32_bf16(af1, bfrag[1][3], acc3, 0, 0, 0);
        ushort_t* yp = Y + (size_t)(row0 + lg * 4) * 64 + l15;
#pragma unroll
        for (int r = 0; r < 4; ++r) {
            yp[(size_t)r * 64 + 0]  = (ushort_t)f2bf(acc0[r]);
            yp[(size_t)r * 64 + 16] = (ushort_t)f2bf(acc1[r]);
            yp[(size_t)r * 64 + 32] = (ushort_t)f2bf(acc2[r]);
            yp[(size_t)r * 64 + 48] = (ushort_t)f2bf(acc3[r]);
        }
    }
}

// ---------------- row-per-wave GEMM: Y = op(X) @ W [+bias][relu], fp32 or bf16 out ----------------
template<int MB, bool RIN, bool ROUT, bool OBF16>
__global__ __launch_bounds__(256) void k_gemm_rowwave(const float* __restrict__ X, const float* __restrict__ W,
                                                      const float* __restrict__ bias, void* __restrict__ Yv,
                                                      int N, int K) {
    extern __shared__ float Wl[];
    const int M = MB * 64;
    for (int idx = threadIdx.x; idx < K * M; idx += 256) Wl[idx] = W[idx];
    __syncthreads();
    int lane = threadIdx.x & 63;
    int gw = blockIdx.x * 4 + (threadIdx.x >> 6);
    int tw = gridDim.x * 4;
    const int K4 = K >> 2;
    for (int row = gw; row < N; row += tw) {
        float acc[MB];
#pragma unroll
        for (int cb = 0; cb < MB; ++cb) acc[cb] = 0.f;
        const float4* xr = (const float4*)(X + (size_t)row * K);
        for (int k4 = 0; k4 < K4; ++k4) {
            float4 xv = xr[k4];
            if (RIN) {
                xv.x = fmaxf(xv.x, 0.f); xv.y = fmaxf(xv.y, 0.f);
                xv.z = fmaxf(xv.z, 0.f); xv.w = fmaxf(xv.w, 0.f);
            }
            const float* wp = Wl + (k4 * 4) * M + lane;
#pragma unroll
            for (int cb = 0; cb < MB; ++cb) acc[cb] = fmaf(xv.x, wp[cb * 64], acc[cb]);
            wp += M;
#pragma unroll
            for (int cb = 0; cb < MB; ++cb) acc[cb] = fmaf(xv.y, wp[cb * 64], acc[cb]);
            wp += M;
#pragma unroll
            for (int cb = 0; cb < MB; ++cb) acc[cb] = fmaf(xv.z, wp[cb * 64], acc[cb]);
            wp += M;
#pragma unroll
            for (int cb = 0; cb < MB; ++cb) acc[cb] = fmaf(xv.w, wp[cb * 64], acc[cb]);
        }
#pragma unroll
        for (int cb = 0; cb < MB; ++cb) {
            float y = acc[cb];
            int col = cb * 64 + lane;
            if (bias) y += bias[col];
            if (ROUT) y = fmaxf(y, 0.f);
            if (OBF16) ((ushort_t*)Yv)[(size_t)row * M + col] = (ushort_t)f2bf(y);
            else ((float*)Yv)[(size_t)row * M + col] = y;
        }
    }
}

// ---------------- ROI pool partials: LDS accumulate per (graph, part), merge to global ----------------
__global__ __launch_bounds__(256) void k_pool_part(const float* __restrict__ A, const int* __restrict__ roi,
                                                   float* __restrict__ sums, float* __restrict__ cnt,
                                                   int npg, int bpg) {
    int b = blockIdx.x / bpg;
    int part = blockIdx.x - b * bpg;
    __shared__ float ls[RRv * 64];
    __shared__ int lc[RRv];
    int tid = threadIdx.x;
    for (int idx = tid; idx < RRv * 64; idx += 256) ls[idx] = 0.f;
    for (int idx = tid; idx < RRv; idx += 256) lc[idx] = 0;
    __syncthreads();
    int wv = tid >> 6, lane = tid & 63;
    int wig = part * 4 + wv, stride = bpg * 4;
    for (int i = wig; i < npg; i += stride) {
        int node = b * npg + i;
        int r = roi[node];
        atomicAdd(&ls[r * 64 + lane], fmaxf(A[(size_t)node * 64 + lane], 0.f));
        if (lane == 0) atomicAdd(&lc[r], 1);
    }
    __syncthreads();
    float* sb = sums + (size_t)b * RRv * 64;
    for (int idx = tid; idx < RRv * 64; idx += 256) {
        float v = ls[idx];
        if (v != 0.f) atomicAdd(&sb[idx], v);
    }
    for (int idx = tid; idx < RRv; idx += 256) {
        int c = lc[idx];
        if (c) atomicAdd(&cnt[b * RRv + idx], (float)c);
    }
}

__global__ __launch_bounds__(256) void k_pool_fin(const float* __restrict__ sums, const float* __restrict__ cnt,
                                                  float* __restrict__ outp, int total) {
    int i = blockIdx.x * 256 + threadIdx.x;
    if (i < total) outp[i] = sums[i] / fmaxf(cnt[i >> 6], 1.f);
}

__global__ __launch_bounds__(256) void k_pool_fin2(const float* __restrict__ sums, const float* __restrict__ cnt,
                                                   const float* __restrict__ other, float* __restrict__ outp,
                                                   float* __restrict__ comb, int total) {
    int i = blockIdx.x * 256 + threadIdx.x;
    if (i < total) {
        float v = sums[i] / fmaxf(cnt[i >> 6], 1.f);
        outp[i] = v;
        comb[i] = v + other[i];
    }
}

// ---------------- transpose W(rows,cols) -> Wt(cols,rows) ----------------
__global__ __launch_bounds__(256) void k_transpose(const float* __restrict__ W, float* __restrict__ Wt,
                                                   int rows, int cols) {
    int i = blockIdx.x * 256 + threadIdx.x;
    if (i < rows * cols) {
        int r = i / cols, c = i - r * cols;
        Wt[c * rows + r] = W[i];
    }
}

// ---------------- attention: one block per (b,h) ----------------
__global__ __launch_bounds__(256) void k_attn(const float* __restrict__ qkv, float* __restrict__ aw,
                                              float* __restrict__ o) {
    int bh = blockIdx.x;
    int b = bh >> 2, h = bh & 3;
    __shared__ float qs[148][16];
    __shared__ float kT[16][152];
    __shared__ float vs[148][16];
    __shared__ float ps[4][152];
    int tid = threadIdx.x;
    const float* base = qkv + (size_t)b * 148 * 192 + h * 16;
    for (int idx = tid; idx < 148 * 16; idx += 256) {
        int i = idx >> 4, d = idx & 15;
        const float* p = base + (size_t)i * 192 + d;
        qs[i][d] = p[0] * 0.25f;
        kT[d][i] = p[64];
        vs[i][d] = p[128];
    }
    __syncthreads();
    int wv = tid >> 6, lane = tid & 63;
    float* aw_bh = aw + (size_t)bh * 148 * 148;
    for (int i = wv; i < 148; i += 4) {
        float s0 = 0.f, s1 = 0.f, s2 = 0.f;
#pragma unroll
        for (int d = 0; d < 16; ++d) {
            float q = qs[i][d];
            s0 = fmaf(q, kT[d][lane], s0);
            s1 = fmaf(q, kT[d][lane + 64], s1);
            if (lane < 20) s2 = fmaf(q, kT[d][lane + 128], s2);
        }
        float m = fmaxf(s0, s1);
        if (lane < 20) m = fmaxf(m, s2);
#pragma unroll
        for (int off = 1; off < 64; off <<= 1) m = fmaxf(m, __shfl_xor(m, off));
        float e0 = __expf(s0 - m), e1 = __expf(s1 - m);
        float e2 = (lane < 20) ? __expf(s2 - m) : 0.f;
        float sum = e0 + e1 + e2;
#pragma unroll
        for (int off = 1; off < 64; off <<= 1) sum += __shfl_xor(sum, off);
        float inv = 1.f / sum;
        float p0 = e0 * inv, p1 = e1 * inv, p2 = e2 * inv;
        float* awr = aw_bh + (size_t)i * 148;
        awr[lane] = p0;
        awr[lane + 64] = p1;
        if (lane < 20) awr[lane + 128] = p2;
        ps[wv][lane] = p0;
        ps[wv][lane + 64] = p1;
        if (lane < 20) ps[wv][lane + 128] = p2;
        int d = lane & 15, jj = lane >> 4;
        float acc = 0.f;
        for (int t = jj; t < 148; t += 4) acc = fmaf(ps[wv][t], vs[t][d], acc);
        acc += __shfl_xor(acc, 16);
        acc += __shfl_xor(acc, 32);
        if (lane < 16) o[((size_t)b * 148 + i) * 64 + h * 16 + d] = acc;
    }
}

// ---------------- fused GEMM + bias + residual + LayerNorm (K=M=64) ----------------
__global__ __launch_bounds__(256) void k_ln_gemm(const float* __restrict__ X, const float* __restrict__ Wt,
                                                 const float* __restrict__ bias, const float* __restrict__ resid,
                                                 const float* __restrict__ g, const float* __restrict__ bb,
                                                 float* __restrict__ Y, int N) {
    __shared__ float Wl[4096];
    for (int idx = threadIdx.x; idx < 4096; idx += 256) Wl[idx] = Wt[idx];
    __syncthreads();
    int lane = threadIdx.x & 63;
    int gw = blockIdx.x * 4 + (threadIdx.x >> 6);
    int tw = gridDim.x * 4;
    for (int row = gw; row < N; row += tw) {
        const float4* xr = (const float4*)(X + (size_t)row * 64);
        float acc = 0.f;
        for (int k4 = 0; k4 < 16; ++k4) {
            float4 xv = xr[k4];
            const float* wp = Wl + (k4 * 4) * 64 + lane;
            acc = fmaf(xv.x, wp[0], acc);
            acc = fmaf(xv.y, wp[64], acc);
            acc = fmaf(xv.z, wp[128], acc);
            acc = fmaf(xv.w, wp[192], acc);
        }
        float y = acc + bias[lane] + resid[(size_t)row * 64 + lane];
        float s = y;
#pragma unroll
        for (int off = 1; off < 64; off <<= 1) s += __shfl_xor(s, off);
        float mu = s * (1.f / 64.f);
        float dcen = y - mu;
        float v = dcen * dcen;
#pragma unroll
        for (int off = 1; off < 64; off <<= 1) v += __shfl_xor(v, off);
        float var = v * (1.f / 64.f);
        Y[(size_t)row * 64 + lane] = dcen * rsqrtf(var + 1e-5f) * g[lane] + bb[lane];
    }
}

// ---------------- classifier stage A: partial GEMM, no atomics ----------------
__global__ __launch_bounds__(256) void k_cls_part(const float* __restrict__ T, const float* __restrict__ Wc1,
                                                  float* __restrict__ Zp) {
    int ks = blockIdx.x >> 2;
    int mt = blockIdx.x & 3;
    int k0 = ks * 74;
    int m0 = mt * 256;
    __shared__ float Tl[64][74];
    int tid = threadIdx.x;
    for (int idx = tid; idx < 64 * 74; idx += 256) {
        int b = idx / 74, kk = idx - b * 74;
        Tl[b][kk] = T[(size_t)b * 9472 + k0 + kk];
    }
    __syncthreads();
    int lane = tid & 63, bq = tid >> 6;
    int mbase = m0 + lane * 4;
    size_t moff = (mbase + 3 < 1000) ? (size_t)mbase : 0;
    float4 acc[16];
#pragma unroll
    for (int j = 0; j < 16; ++j) acc[j] = make_float4(0.f, 0.f, 0.f, 0.f);
#pragma unroll 2
    for (int kk = 0; kk < 74; ++kk) {
        float4 w = *(const float4*)(Wc1 + (size_t)(k0 + kk) * 1000 + moff);
#pragma unroll
        for (int j = 0; j < 16; ++j) {
            float t = Tl[bq * 16 + j][kk];
            acc[j].x = fmaf(t, w.x, acc[j].x);
            acc[j].y = fmaf(t, w.y, acc[j].y);
            acc[j].z = fmaf(t, w.z, acc[j].z);
            acc[j].w = fmaf(t, w.w, acc[j].w);
        }
    }
    float* zp = Zp + (size_t)ks * 64 * 1024;
#pragma unroll
    for (int j = 0; j < 16; ++j) {
        int b = bq * 16 + j;
        *(float4*)(zp + (size_t)b * 1024 + mbase) = acc[j];
    }
}

// ---------------- classifier stage B: reduce partials + bias + BN + leaky ----------------
__global__ __launch_bounds__(256) void k_cls_reduce(const float* __restrict__ Zp, const float* __restrict__ bc1,
                                                    const float* __restrict__ bn_g, const float* __restrict__ bn_b,
                                                    float* __restrict__ zb) {
    int flat = blockIdx.x * 256 + threadIdx.x;
    int b = flat >> 10, m = flat & 1023;
    if (m >= 1000) return;
    float s = 0.f;
    for (int ks = 0; ks < 128; ++ks)
        s += Zp[((size_t)ks * 64 + b) * 1024 + m];
    float rs = rsqrtf(1.0f + 1e-5f);
    float z = bn_g[m] * (s + bc1[m]) * rs + bn_b[m];
    zb[flat] = z >= 0.f ? z : 0.01f * z;
}

// ---------------- classifier finish: 1000 -> 2 matvec ----------------
__global__ __launch_bounds__(256) void k_cls_final(const float* __restrict__ zb,
                                                   const float* __restrict__ Wc2, const float* __restrict__ bc2,
                                                   float* __restrict__ out) {
    int b = blockIdx.x;
    int tid = threadIdx.x;
    float a0 = 0.f, a1 = 0.f;
    for (int m = tid; m < 1000; m += 256) {
        float z = zb[b * 1024 + m];
        a0 = fmaf(z, Wc2[m * 2], a0);
        a1 = fmaf(z, Wc2[m * 2 + 1], a1);
    }
#pragma unroll
    for (int off = 1; off < 64; off <<= 1) {
        a0 += __shfl_xor(a0, off);
        a1 += __shfl_xor(a1, off);
    }
    __shared__ float r0[4], r1[4];
    if ((tid & 63) == 0) { r0[tid >> 6] = a0; r1[tid >> 6] = a1; }
    __syncthreads();
    if (tid == 0) {
        out[b * 2 + 0] = r0[0] + r0[1] + r0[2] + r0[3] + bc2[0];
        out[b * 2 + 1] = r1[0] + r1[1] + r1[2] + r1[3] + bc2[1];
    }
}

extern "C" void kernel_launch(void* const* d_in, const int* in_sizes, int n_in,
                              void* d_out, int out_size, void* d_ws, size_t ws_size,
                              hipStream_t stream) {
    (void)in_sizes; (void)n_in; (void)out_size; (void)ws_size;

    const float* x_feat = (const float*)d_in[0];
    const int* node_roi = (const int*)d_in[1];
    const int* ei1 = (const int*)d_in[3];
    const float* ew1 = (const float*)d_in[4];
    const float* x2f = (const float*)d_in[5];
    const int* roi2 = (const int*)d_in[6];
    const int* ei2 = (const int*)d_in[8];
    const float* ew2 = (const float*)d_in[9];
    const float* Wg1 = (const float*)d_in[10];
    const float* bg1 = (const float*)d_in[11];
    const float* Wg2 = (const float*)d_in[12];
    const float* bg2 = (const float*)d_in[13];
    const float* Wr1 = (const float*)d_in[14];
    const float* br1 = (const float*)d_in[15];
    const float* Wr2 = (const float*)d_in[16];
    const float* br2 = (const float*)d_in[17];
    const float* in_proj_w = (const float*)d_in[18];
    const float* in_proj_b = (const float*)d_in[19];
    const float* out_proj_w = (const float*)d_in[20];
    const float* out_proj_b = (const float*)d_in[21];
    const float* ln1_g = (const float*)d_in[22];
    const float* ln1_b = (const float*)d_in[23];
    const float* ff_w1 = (const float*)d_in[24];
    const float* ff_b1 = (const float*)d_in[25];
    const float* ff_w2 = (const float*)d_in[26];
    const float* ff_b2 = (const float*)d_in[27];
    const float* ln2_g = (const float*)d_in[28];
    const float* ln2_b = (const float*)d_in[29];
    const float* Wc1 = (const float*)d_in[30];
    const float* bc1 = (const float*)d_in[31];
    const float* bn_g = (const float*)d_in[32];
    const float* bn_b = (const float*)d_in[33];
    const float* Wc2 = (const float*)d_in[34];
    const float* bc2 = (const float*)d_in[35];

    const int* src1 = ei1;
    const int* dst1 = ei1 + E1v;
    const int* src2 = ei2;
    const int* dst2 = ei2 + E2v;

    float* out = (float*)d_out;
    const int PSZ = BRv * 64;
    float* pooled_out = out + 128;
    float* pooledroi_out = out + 128 + PSZ;
    float* tout_out = out + 128 + 2 * PSZ;
    float* attn_out = out + 128 + 3 * PSZ;

    // ===== workspace layout (floats) =====
    float* W = (float*)d_ws;
    size_t o = 0;
    float* dinv1 = W + o;       o += N1v;
    int* counts1 = (int*)(W + o); o += N1v;
    float* dinv2 = W + o;       o += N2v;
    int* counts2 = (int*)(W + o); o += N2v;
    float* sums1 = W + o;       o += PSZ;
    float* cnt1 = W + o;        o += BRv;
    float* sums2 = W + o;       o += PSZ;
    float* cnt2 = W + o;        o += BRv;
    float* zbuf = W + o;        o += BBv * 1024;
    size_t zone_elems = o;
    int* offs1 = (int*)(W + o); o += N1v;
    int* aux1 = (int*)(W + o);  o += 256;
    int* srcC1 = (int*)(W + o); o += E1v;
    float* normC1 = W + o;      o += E1v;
    int* offs2 = (int*)(W + o); o += N2v;
    int* aux2 = (int*)(W + o);  o += 256;
    int* srcC2 = (int*)(W + o); o += E2v;
    float* normC2 = W + o;      o += E2v;
    float* h1Pf = W + o; size_t h1P_off = o; o += (size_t)N1v * 64;  // bf16 uses half
    float* h1A = W + o; size_t h1A_off = o; o += (size_t)N1v * 64;
    ushort_t* h1P = (ushort_t*)h1Pf;
    size_t p = h1P_off;
    ushort_t* h2P = (ushort_t*)(W + p);  p += (size_t)N2v * 64;
    float* h2A = W + p;  p += (size_t)N2v * 64;
    float* comb = W + p; p += PSZ;
    float* qkvb = W + p; p += (size_t)BRv * 192;
    float* obuf = W + p; p += PSZ;
    float* xbuf = W + p; p += PSZ;
    float* f1 = W + p;   p += PSZ;
    float* WinT = W + p; p += 64 * 192;
    float* WoutT = W + p; p += 64 * 64;
    float* Zp = W + h1A_off;   // 128*64*1024 floats, aliased onto dead h1A

    dim3 blk(256);

    hipMemsetAsync(W, 0, zone_elems * sizeof(float), stream);

    // ===== branch 1 (node graph): CSR build =====
    k_deg_hist<<<E1v / 256, blk, 0, stream>>>(dst1, ew1, dinv1, counts1, E1v);
    k_dinv<<<N1v / 256, blk, 0, stream>>>(dinv1, N1v);
    k_scan1<<<N1v / 1024, blk, 0, stream>>>(counts1, offs1, aux1, N1v);
    k_scan2<<<1, blk, 0, stream>>>(aux1, N1v / 1024);
    k_scan3<<<N1v / 256, blk, 0, stream>>>(offs1, aux1, counts1, N1v);
    k_fill<<<E1v / 256, blk, 0, stream>>>(src1, dst1, ew1, dinv1, counts1, srcC1, normC1, E1v);
    // layers (MFMA bf16 GEMMs -> bf16 P, batched gather)
    k_gemm_mfma<false><<<2048, blk, 0, stream>>>(x_feat, Wg1, h1P, N1v);
    k_edge_gather2<<<4096, blk, 0, stream>>>(srcC1, normC1, offs1, h1P, dinv1, bg1, h1A, N1v, E1v);
    k_gemm_mfma<true><<<2048, blk, 0, stream>>>(h1A, Wg2, h1P, N1v);
    k_edge_gather2<<<4096, blk, 0, stream>>>(srcC1, normC1, offs1, h1P, dinv1, bg2, h1A, N1v, E1v);
    k_pool_part<<<BBv * 4, blk, 0, stream>>>(h1A, node_roi, sums1, cnt1, N1v / BBv, 4);
    k_pool_fin<<<cdiv(PSZ, 256), blk, 0, stream>>>(sums1, cnt1, pooled_out, PSZ);

    // ===== branch 2 (roi graph): CSR build =====
    k_deg_hist<<<E2v / 256, blk, 0, stream>>>(dst2, ew2, dinv2, counts2, E2v);
    k_dinv<<<cdiv(N2v, 256), blk, 0, stream>>>(dinv2, N2v);
    k_scan1<<<cdiv(N2v, 1024), blk, 0, stream>>>(counts2, offs2, aux2, N2v);
    k_scan2<<<1, blk, 0, stream>>>(aux2, cdiv(N2v, 1024));
    k_scan3<<<cdiv(N2v, 256), blk, 0, stream>>>(offs2, aux2, counts2, N2v);
    k_fill<<<E2v / 256, blk, 0, stream>>>(src2, dst2, ew2, dinv2, counts2, srcC2, normC2, E2v);
    // layers
    k_gemm_rowwave<1, false, false, true><<<cdiv(N2v, 4), blk, 148 * 64 * 4, stream>>>(x2f, Wr1, nullptr, h2P, N2v, 148);
    k_edge_gather2<<<cdiv(N2v, 4), blk, 0, stream>>>(srcC2, normC2, offs2, h2P, dinv2, br1, h2A, N2v, E2v);
    k_gemm_mfma<true><<<148, blk, 0, stream>>>(h2A, Wr2, h2P, N2v);
    k_edge_gather2<<<cdiv(N2v, 4), blk, 0, stream>>>(srcC2, normC2, offs2, h2P, dinv2, br2, h2A, N2v, E2v);
    k_pool_part<<<BBv, blk, 0, stream>>>(h2A, roi2, sums2, cnt2, RRv, 1);
    k_pool_fin2<<<cdiv(PSZ, 256), blk, 0, stream>>>(sums2, cnt2, pooled_out, pooledroi_out, comb, PSZ);

    // ===== transformer =====
    k_transpose<<<cdiv(192 * 64, 256), blk, 0, stream>>>(in_proj_w, WinT, 192, 64);
    k_transpose<<<cdiv(64 * 64, 256), blk, 0, stream>>>(out_proj_w, WoutT, 64, 64);
    k_gemm_rowwave<3, false, false, false><<<cdiv(N2v, 4), blk, 64 * 192 * 4, stream>>>(comb, WinT, in_proj_b, qkvb, N2v, 64);
    k_attn<<<BBv * 4, blk, 0, stream>>>(qkvb, attn_out, obuf);
    k_ln_gemm<<<cdiv(N2v, 4), blk, 0, stream>>>(obuf, WoutT, out_proj_b, comb, ln1_g, ln1_b, xbuf, N2v);
    k_gemm_rowwave<1, false, true, false><<<cdiv(N2v, 4), blk, 64 * 64 * 4, stream>>>(xbuf, ff_w1, ff_b1, f1, N2v, 64);
    k_ln_gemm<<<cdiv(N2v, 4), blk, 0, stream>>>(f1, ff_w2, ff_b2, xbuf, ln2_g, ln2_b, tout_out, N2v);

    // ===== classifier =====
    k_cls_part<<<512, blk, 0, stream>>>(tout_out, Wc1, Zp);
    k_cls_reduce<<<BBv * 1024 / 256, blk, 0, stream>>>(Zp, bc1, bn_g, bn_b, zbuf);
    k_cls_final<<<BBv, blk, 0, stream>>>(zbuf, Wc2, bc2, out);
}

// Round 6
// 721.066 us; speedup vs baseline: 2.1103x; 1.1008x over previous
//
#include <hip/hip_runtime.h>
#include <cstdint>
#include <cstddef>

#define N1v 262144
#define E1v 1048576
#define N2v 9472
#define E2v 262144
#define BBv 64
#define RRv 148
#define HIDv 1000
#define BRv (BBv * RRv)

static inline int cdiv(int a, int b) { return (a + b - 1) / b; }

typedef __attribute__((ext_vector_type(8))) short bf16x8;
typedef __attribute__((ext_vector_type(4))) float f32x4;
typedef unsigned short ushort_t;

__device__ inline short f2bf(float f) {
    union { float f; unsigned u; } v; v.f = f;
    unsigned r = v.u + 0x7fff + ((v.u >> 16) & 1);   // RNE
    return (short)(r >> 16);
}
__device__ inline float bf2f(unsigned hs) {
    union { unsigned u; float f; } v; v.u = hs << 16; return v.f;
}

// ---------------- fused degree + histogram ----------------
__global__ __launch_bounds__(256) void k_deg_hist(const int* __restrict__ dst, const float* __restrict__ ew,
                                                  float* __restrict__ deg, int* __restrict__ counts, int E) {
    int i = blockIdx.x * 256 + threadIdx.x;
    if (i < E) {
        int d = dst[i];
        atomicAdd(&deg[d], ew[i]);
        atomicAdd(&counts[d], 1);
    }
}

__global__ __launch_bounds__(256) void k_dinv(float* __restrict__ deg, int N) {
    int i = blockIdx.x * 256 + threadIdx.x;
    if (i < N) deg[i] = rsqrtf(deg[i] + 1.0f);
}

// ---------------- 3-kernel exclusive scan (1024 elems/block) ----------------
__global__ __launch_bounds__(256) void k_scan1(const int* __restrict__ counts, int* __restrict__ offs,
                                               int* __restrict__ aux, int N) {
    __shared__ int tmp[256];
    int t = threadIdx.x;
    int base = blockIdx.x * 1024 + t * 4;
    int v0 = 0, v1 = 0, v2 = 0, v3 = 0;
    if (base + 3 < N) {
        int4 c = *(const int4*)(counts + base);
        v0 = c.x; v1 = c.y; v2 = c.z; v3 = c.w;
    } else {
        if (base < N) v0 = counts[base];
        if (base + 1 < N) v1 = counts[base + 1];
        if (base + 2 < N) v2 = counts[base + 2];
    }
    int tsum = v0 + v1 + v2 + v3;
    tmp[t] = tsum;
    __syncthreads();
    int val = tsum;
    for (int off = 1; off < 256; off <<= 1) {
        int other = (t >= off) ? tmp[t - off] : 0;
        __syncthreads();
        val += other;
        tmp[t] = val;
        __syncthreads();
    }
    int excl = val - tsum;
    if (base < N) offs[base] = excl;
    if (base + 1 < N) offs[base + 1] = excl + v0;
    if (base + 2 < N) offs[base + 2] = excl + v0 + v1;
    if (base + 3 < N) offs[base + 3] = excl + v0 + v1 + v2;
    if (t == 255) aux[blockIdx.x] = val;
}

__global__ __launch_bounds__(256) void k_scan2(int* __restrict__ aux, int nb) {
    __shared__ int tmp[256];
    int t = threadIdx.x;
    int v = (t < nb) ? aux[t] : 0;
    tmp[t] = v;
    __syncthreads();
    int val = v;
    for (int off = 1; off < 256; off <<= 1) {
        int other = (t >= off) ? tmp[t - off] : 0;
        __syncthreads();
        val += other;
        tmp[t] = val;
        __syncthreads();
    }
    if (t < nb) aux[t] = val - v;
}

__global__ __launch_bounds__(256) void k_scan3(int* __restrict__ offs, const int* __restrict__ aux,
                                               int* __restrict__ cursor, int N) {
    int i = blockIdx.x * 256 + threadIdx.x;
    if (i < N) {
        int val = offs[i] + aux[i >> 10];
        offs[i] = val;
        cursor[i] = val;
    }
}

// ---------------- CSR fill (+ fused sym-norm computation) ----------------
__global__ __launch_bounds__(256) void k_fill(const int* __restrict__ src, const int* __restrict__ dst,
                                              const float* __restrict__ ew, const float* __restrict__ dinv,
                                              int* __restrict__ cursor, int* __restrict__ srcC,
                                              float* __restrict__ normC, int E) {
    int e = blockIdx.x * 256 + threadIdx.x;
    if (e < E) {
        int s = src[e], d = dst[e];
        float nv = dinv[s] * ew[e] * dinv[d];
        int j = atomicAdd(&cursor[d], 1);
        srcC[j] = s;
        normC[j] = nv;
    }
}

// ---------------- edge gather v2: 4 edge-slots x 16 lanes, bf16 P rows ----------------
__global__ __launch_bounds__(256) void k_edge_gather2(const int* __restrict__ srcC, const float* __restrict__ normC,
                                                      const int* __restrict__ offs, const ushort_t* __restrict__ Pb,
                                                      const float* __restrict__ dinv, const float* __restrict__ bias,
                                                      float* __restrict__ A, int N, int E) {
    int tid = threadIdx.x;
    int lane = tid & 63;
    int es = lane >> 4;        // edge slot 0..3
    int fq = lane & 15;        // feature quarter (4 floats)
    float4 bv = *(const float4*)(bias + fq * 4);
    int gw = blockIdx.x * 4 + (tid >> 6);
    int tw = gridDim.x * 4;
    for (int i = gw; i < N; i += tw) {
        int beg = offs[i];
        int end = (i + 1 < N) ? offs[i + 1] : E;
        float ax = 0.f, ay = 0.f, az = 0.f, aw = 0.f;
        for (int j = beg + es; j < end; j += 4) {
            int s = srcC[j];
            float nv = normC[j];
            uint2 w = *(const uint2*)(Pb + (size_t)s * 64 + fq * 4);
            ax = fmaf(nv, bf2f(w.x & 0xffffu), ax);
            ay = fmaf(nv, bf2f(w.x >> 16), ay);
            az = fmaf(nv, bf2f(w.y & 0xffffu), az);
            aw = fmaf(nv, bf2f(w.y >> 16), aw);
        }
        ax += __shfl_xor(ax, 16); ay += __shfl_xor(ay, 16);
        az += __shfl_xor(az, 16); aw += __shfl_xor(aw, 16);
        ax += __shfl_xor(ax, 32); ay += __shfl_xor(ay, 32);
        az += __shfl_xor(az, 32); aw += __shfl_xor(aw, 32);
        if (es == 0) {
            float di = dinv[i];
            float s2 = di * di;
            uint2 w = *(const uint2*)(Pb + (size_t)i * 64 + fq * 4);
            float4 r;
            r.x = fmaf(s2, bf2f(w.x & 0xffffu), ax) + bv.x;
            r.y = fmaf(s2, bf2f(w.x >> 16), ay) + bv.y;
            r.z = fmaf(s2, bf2f(w.y & 0xffffu), az) + bv.z;
            r.w = fmaf(s2, bf2f(w.y >> 16), aw) + bv.w;
            *(float4*)(A + (size_t)i * 64 + fq * 4) = r;
        }
    }
}

// ---------------- MFMA bf16 GEMM: Yb(N,64) = bf16( op(X)(N,64) @ W(64,64) ) ----------------
template<bool RIN>
__global__ __launch_bounds__(256) void k_gemm_mfma(const float* __restrict__ X, const float* __restrict__ Wmat,
                                                   ushort_t* __restrict__ Y, int N) {
    int tid = threadIdx.x;
    int lane = tid & 63;
    int wv = tid >> 6;
    int l15 = lane & 15;
    int lg = lane >> 4;
    bf16x8 bfrag[2][4];
    for (int kh = 0; kh < 2; ++kh)
        for (int ct = 0; ct < 4; ++ct) {
            bf16x8 b;
#pragma unroll
            for (int i = 0; i < 8; ++i)
                b[i] = f2bf(Wmat[(size_t)(kh * 32 + lg * 8 + i) * 64 + ct * 16 + l15]);
            bfrag[kh][ct] = b;
        }
    int gw = blockIdx.x * 4 + wv;
    int tw = gridDim.x * 4;
    int ntiles = N >> 4;
    for (int t = gw; t < ntiles; t += tw) {
        int row0 = t << 4;
        const float* xp = X + (size_t)(row0 + l15) * 64 + lg * 8;
        float4 a0 = *(const float4*)(xp);
        float4 a1 = *(const float4*)(xp + 4);
        float4 a2 = *(const float4*)(xp + 32);
        float4 a3 = *(const float4*)(xp + 36);
        if (RIN) {
            a0.x = fmaxf(a0.x, 0.f); a0.y = fmaxf(a0.y, 0.f); a0.z = fmaxf(a0.z, 0.f); a0.w = fmaxf(a0.w, 0.f);
            a1.x = fmaxf(a1.x, 0.f); a1.y = fmaxf(a1.y, 0.f); a1.z = fmaxf(a1.z, 0.f); a1.w = fmaxf(a1.w, 0.f);
            a2.x = fmaxf(a2.x, 0.f); a2.y = fmaxf(a2.y, 0.f); a2.z = fmaxf(a2.z, 0.f); a2.w = fmaxf(a2.w, 0.f);
            a3.x = fmaxf(a3.x, 0.f); a3.y = fmaxf(a3.y, 0.f); a3.z = fmaxf(a3.z, 0.f); a3.w = fmaxf(a3.w, 0.f);
        }
        bf16x8 af0, af1;
        af0[0] = f2bf(a0.x); af0[1] = f2bf(a0.y); af0[2] = f2bf(a0.z); af0[3] = f2bf(a0.w);
        af0[4] = f2bf(a1.x); af0[5] = f2bf(a1.y); af0[6] = f2bf(a1.z); af0[7] = f2bf(a1.w);
        af1[0] = f2bf(a2.x); af1[1] = f2bf(a2.y); af1[2] = f2bf(a2.z); af1[3] = f2bf(a2.w);
        af1[4] = f2bf(a3.x); af1[5] = f2bf(a3.y); af1[6] = f2bf(a3.z); af1[7] = f2bf(a3.w);
        f32x4 acc0 = {0.f, 0.f, 0.f, 0.f}, acc1 = acc0, acc2 = acc0, acc3 = acc0;
        acc0 = __builtin_amdgcn_mfma_f32_16x16x32_bf16(af0, bfrag[0][0], acc0, 0, 0, 0);
        acc1 = __builtin_amdgcn_mfma_f32_16x16x32_bf16(af0, bfrag[0][1], acc1, 0, 0, 0);
        acc2 = __builtin_amdgcn_mfma_f32_16x16x32_bf16(af0, bfrag[0][2], acc2, 0, 0, 0);
        acc3 = __builtin_amdgcn_mfma_f32_16x16x32_bf16(af0, bfrag[0][3], acc3, 0, 0, 0);
        acc0 = __builtin_amdgcn_mfma_f32_16x16x32_bf16(af1, bfrag[1][0], acc0, 0, 0, 0);
        acc1 = __builtin_amdgcn_mfma_f32_16x16x32_bf16(af1, bfrag[1][1], acc1, 0, 0, 0);
        acc2 = __builtin_amdgcn_mfma_f32_16x16x32_bf16(af1, bfrag[1][2], acc2, 0, 0, 0);
        acc3 = __builtin_amdgcn_mfma_f32_16x16x32_bf16(af1, bfrag[1][3], acc3, 0, 0, 0);
        ushort_t* yp = Y + (size_t)(row0 + lg * 4) * 64 + l15;
#pragma unroll
        for (int r = 0; r < 4; ++r) {
            yp[(size_t)r * 64 + 0]  = (ushort_t)f2bf(acc0[r]);
            yp[(size_t)r * 64 + 16] = (ushort_t)f2bf(acc1[r]);
            yp[(size_t)r * 64 + 32] = (ushort_t)f2bf(acc2[r]);
            yp[(size_t)r * 64 + 48] = (ushort_t)f2bf(acc3[r]);
        }
    }
}

// ---------------- row-per-wave GEMM: Y = op(X) @ W [+bias][relu], fp32 or bf16 out ----------------
template<int MB, bool RIN, bool ROUT, bool OBF16>
__global__ __launch_bounds__(256) void k_gemm_rowwave(const float* __restrict__ X, const float* __restrict__ W,
                                                      const float* __restrict__ bias, void* __restrict__ Yv,
                                                      int N, int K) {
    extern __shared__ float Wl[];
    const int M = MB * 64;
    for (int idx = threadIdx.x; idx < K * M; idx += 256) Wl[idx] = W[idx];
    __syncthreads();
    int lane = threadIdx.x & 63;
    int gw = blockIdx.x * 4 + (threadIdx.x >> 6);
    int tw = gridDim.x * 4;
    const int K4 = K >> 2;
    for (int row = gw; row < N; row += tw) {
        float acc[MB];
#pragma unroll
        for (int cb = 0; cb < MB; ++cb) acc[cb] = 0.f;
        const float4* xr = (const float4*)(X + (size_t)row * K);
        for (int k4 = 0; k4 < K4; ++k4) {
            float4 xv = xr[k4];
            if (RIN) {
                xv.x = fmaxf(xv.x, 0.f); xv.y = fmaxf(xv.y, 0.f);
                xv.z = fmaxf(xv.z, 0.f); xv.w = fmaxf(xv.w, 0.f);
            }
            const float* wp = Wl + (k4 * 4) * M + lane;
#pragma unroll
            for (int cb = 0; cb < MB; ++cb) acc[cb] = fmaf(xv.x, wp[cb * 64], acc[cb]);
            wp += M;
#pragma unroll
            for (int cb = 0; cb < MB; ++cb) acc[cb] = fmaf(xv.y, wp[cb * 64], acc[cb]);
            wp += M;
#pragma unroll
            for (int cb = 0; cb < MB; ++cb) acc[cb] = fmaf(xv.z, wp[cb * 64], acc[cb]);
            wp += M;
#pragma unroll
            for (int cb = 0; cb < MB; ++cb) acc[cb] = fmaf(xv.w, wp[cb * 64], acc[cb]);
        }
#pragma unroll
        for (int cb = 0; cb < MB; ++cb) {
            float y = acc[cb];
            int col = cb * 64 + lane;
            if (bias) y += bias[col];
            if (ROUT) y = fmaxf(y, 0.f);
            if (OBF16) ((ushort_t*)Yv)[(size_t)row * M + col] = (ushort_t)f2bf(y);
            else ((float*)Yv)[(size_t)row * M + col] = y;
        }
    }
}

// ---------------- ROI pool partials ----------------
__global__ __launch_bounds__(256) void k_pool_part(const float* __restrict__ A, const int* __restrict__ roi,
                                                   float* __restrict__ sums, float* __restrict__ cnt,
                                                   int npg, int bpg) {
    int b = blockIdx.x / bpg;
    int part = blockIdx.x - b * bpg;
    __shared__ float ls[RRv * 64];
    __shared__ int lc[RRv];
    int tid = threadIdx.x;
    for (int idx = tid; idx < RRv * 64; idx += 256) ls[idx] = 0.f;
    for (int idx = tid; idx < RRv; idx += 256) lc[idx] = 0;
    __syncthreads();
    int wv = tid >> 6, lane = tid & 63;
    int wig = part * 4 + wv, stride = bpg * 4;
    for (int i = wig; i < npg; i += stride) {
        int node = b * npg + i;
        int r = roi[node];
        atomicAdd(&ls[r * 64 + lane], fmaxf(A[(size_t)node * 64 + lane], 0.f));
        if (lane == 0) atomicAdd(&lc[r], 1);
    }
    __syncthreads();
    float* sb = sums + (size_t)b * RRv * 64;
    for (int idx = tid; idx < RRv * 64; idx += 256) {
        float v = ls[idx];
        if (v != 0.f) atomicAdd(&sb[idx], v);
    }
    for (int idx = tid; idx < RRv; idx += 256) {
        int c = lc[idx];
        if (c) atomicAdd(&cnt[b * RRv + idx], (float)c);
    }
}

__global__ __launch_bounds__(256) void k_pool_fin(const float* __restrict__ sums, const float* __restrict__ cnt,
                                                  float* __restrict__ outp, int total) {
    int i = blockIdx.x * 256 + threadIdx.x;
    if (i < total) outp[i] = sums[i] / fmaxf(cnt[i >> 6], 1.f);
}

__global__ __launch_bounds__(256) void k_pool_fin2(const float* __restrict__ sums, const float* __restrict__ cnt,
                                                   const float* __restrict__ other, float* __restrict__ outp,
                                                   float* __restrict__ comb, int total) {
    int i = blockIdx.x * 256 + threadIdx.x;
    if (i < total) {
        float v = sums[i] / fmaxf(cnt[i >> 6], 1.f);
        outp[i] = v;
        comb[i] = v + other[i];
    }
}

// ---------------- transpose W(rows,cols) -> Wt(cols,rows) ----------------
__global__ __launch_bounds__(256) void k_transpose(const float* __restrict__ W, float* __restrict__ Wt,
                                                   int rows, int cols) {
    int i = blockIdx.x * 256 + threadIdx.x;
    if (i < rows * cols) {
        int r = i / cols, c = i - r * cols;
        Wt[c * rows + r] = W[i];
    }
}

// ---------------- attention: grid = B*H*4, each block does a 37-query chunk ----------------
__global__ __launch_bounds__(256) void k_attn(const float* __restrict__ qkv, float* __restrict__ aw,
                                              float* __restrict__ o) {
    int qc = blockIdx.x & 3;       // query chunk 0..3 (37 rows each)
    int bh = blockIdx.x >> 2;
    int b = bh >> 2, h = bh & 3;
    __shared__ float qs[37][16];
    __shared__ float kT[16][152];
    __shared__ float vs[148][16];
    __shared__ float ps[4][152];
    int tid = threadIdx.x;
    const float* base = qkv + (size_t)b * 148 * 192 + h * 16;
    for (int idx = tid; idx < 148 * 16; idx += 256) {
        int i = idx >> 4, d = idx & 15;
        const float* p = base + (size_t)i * 192 + d;
        kT[d][i] = p[64];
        vs[i][d] = p[128];
    }
    int q0 = qc * 37;
    for (int idx = tid; idx < 37 * 16; idx += 256) {
        int i = idx >> 4, d = idx & 15;
        qs[i][d] = base[(size_t)(q0 + i) * 192 + d] * 0.25f;   // fold 1/sqrt(16)
    }
    __syncthreads();
    int wv = tid >> 6, lane = tid & 63;
    float* aw_bh = aw + (size_t)bh * 148 * 148;
    for (int ii = wv; ii < 37; ii += 4) {
        int i = q0 + ii;
        float s0 = 0.f, s1 = 0.f, s2 = 0.f;
#pragma unroll
        for (int d = 0; d < 16; ++d) {
            float q = qs[ii][d];
            s0 = fmaf(q, kT[d][lane], s0);
            s1 = fmaf(q, kT[d][lane + 64], s1);
            if (lane < 20) s2 = fmaf(q, kT[d][lane + 128], s2);
        }
        float m = fmaxf(s0, s1);
        if (lane < 20) m = fmaxf(m, s2);
#pragma unroll
        for (int off = 1; off < 64; off <<= 1) m = fmaxf(m, __shfl_xor(m, off));
        float e0 = __expf(s0 - m), e1 = __expf(s1 - m);
        float e2 = (lane < 20) ? __expf(s2 - m) : 0.f;
        float sum = e0 + e1 + e2;
#pragma unroll
        for (int off = 1; off < 64; off <<= 1) sum += __shfl_xor(sum, off);
        float inv = 1.f / sum;
        float p0 = e0 * inv, p1 = e1 * inv, p2 = e2 * inv;
        float* awr = aw_bh + (size_t)i * 148;
        awr[lane] = p0;
        awr[lane + 64] = p1;
        if (lane < 20) awr[lane + 128] = p2;
        ps[wv][lane] = p0;
        ps[wv][lane + 64] = p1;
        if (lane < 20) ps[wv][lane + 128] = p2;
        int d = lane & 15, jj = lane >> 4;
        float acc = 0.f;
        for (int t = jj; t < 148; t += 4) acc = fmaf(ps[wv][t], vs[t][d], acc);
        acc += __shfl_xor(acc, 16);
        acc += __shfl_xor(acc, 32);
        if (lane < 16) o[((size_t)b * 148 + i) * 64 + h * 16 + d] = acc;
    }
}

// ---------------- fused GEMM + bias + residual + LayerNorm (K=M=64) ----------------
__global__ __launch_bounds__(256) void k_ln_gemm(const float* __restrict__ X, const float* __restrict__ Wt,
                                                 const float* __restrict__ bias, const float* __restrict__ resid,
                                                 const float* __restrict__ g, const float* __restrict__ bb,
                                                 float* __restrict__ Y, int N) {
    __shared__ float Wl[4096];
    for (int idx = threadIdx.x; idx < 4096; idx += 256) Wl[idx] = Wt[idx];
    __syncthreads();
    int lane = threadIdx.x & 63;
    int gw = blockIdx.x * 4 + (threadIdx.x >> 6);
    int tw = gridDim.x * 4;
    for (int row = gw; row < N; row += tw) {
        const float4* xr = (const float4*)(X + (size_t)row * 64);
        float acc = 0.f;
        for (int k4 = 0; k4 < 16; ++k4) {
            float4 xv = xr[k4];
            const float* wp = Wl + (k4 * 4) * 64 + lane;
            acc = fmaf(xv.x, wp[0], acc);
            acc = fmaf(xv.y, wp[64], acc);
            acc = fmaf(xv.z, wp[128], acc);
            acc = fmaf(xv.w, wp[192], acc);
        }
        float y = acc + bias[lane] + resid[(size_t)row * 64 + lane];
        float s = y;
#pragma unroll
        for (int off = 1; off < 64; off <<= 1) s += __shfl_xor(s, off);
        float mu = s * (1.f / 64.f);
        float dcen = y - mu;
        float v = dcen * dcen;
#pragma unroll
        for (int off = 1; off < 64; off <<= 1) v += __shfl_xor(v, off);
        float var = v * (1.f / 64.f);
        Y[(size_t)row * 64 + lane] = dcen * rsqrtf(var + 1e-5f) * g[lane] + bb[lane];
    }
}

// ---------------- classifier stage A: partial GEMM, no atomics ----------------
__global__ __launch_bounds__(256) void k_cls_part(const float* __restrict__ T, const float* __restrict__ Wc1,
                                                  float* __restrict__ Zp) {
    int ks = blockIdx.x >> 2;
    int mt = blockIdx.x & 3;
    int k0 = ks * 74;
    int m0 = mt * 256;
    __shared__ float Tl[64][74];
    int tid = threadIdx.x;
    for (int idx = tid; idx < 64 * 74; idx += 256) {
        int b = idx / 74, kk = idx - b * 74;
        Tl[b][kk] = T[(size_t)b * 9472 + k0 + kk];
    }
    __syncthreads();
    int lane = tid & 63, bq = tid >> 6;
    int mbase = m0 + lane * 4;
    size_t moff = (mbase + 3 < 1000) ? (size_t)mbase : 0;
    float4 acc[16];
#pragma unroll
    for (int j = 0; j < 16; ++j) acc[j] = make_float4(0.f, 0.f, 0.f, 0.f);
#pragma unroll 2
    for (int kk = 0; kk < 74; ++kk) {
        float4 w = *(const float4*)(Wc1 + (size_t)(k0 + kk) * 1000 + moff);
#pragma unroll
        for (int j = 0; j < 16; ++j) {
            float t = Tl[bq * 16 + j][kk];
            acc[j].x = fmaf(t, w.x, acc[j].x);
            acc[j].y = fmaf(t, w.y, acc[j].y);
            acc[j].z = fmaf(t, w.z, acc[j].z);
            acc[j].w = fmaf(t, w.w, acc[j].w);
        }
    }
    float* zp = Zp + (size_t)ks * 64 * 1024;
#pragma unroll
    for (int j = 0; j < 16; ++j) {
        int b = bq * 16 + j;
        *(float4*)(zp + (size_t)b * 1024 + mbase) = acc[j];
    }
}

// ---------------- classifier stage B: reduce partials + bias + BN + leaky ----------------
__global__ __launch_bounds__(256) void k_cls_reduce(const float* __restrict__ Zp, const float* __restrict__ bc1,
                                                    const float* __restrict__ bn_g, const float* __restrict__ bn_b,
                                                    float* __restrict__ zb) {
    int flat = blockIdx.x * 256 + threadIdx.x;
    int b = flat >> 10, m = flat & 1023;
    if (m >= 1000) return;
    float s = 0.f;
    for (int ks = 0; ks < 128; ++ks)
        s += Zp[((size_t)ks * 64 + b) * 1024 + m];
    float rs = rsqrtf(1.0f + 1e-5f);
    float z = bn_g[m] * (s + bc1[m]) * rs + bn_b[m];
    zb[flat] = z >= 0.f ? z : 0.01f * z;
}

// ---------------- classifier finish: 1000 -> 2 matvec ----------------
__global__ __launch_bounds__(256) void k_cls_final(const float* __restrict__ zb,
                                                   const float* __restrict__ Wc2, const float* __restrict__ bc2,
                                                   float* __restrict__ out) {
    int b = blockIdx.x;
    int tid = threadIdx.x;
    float a0 = 0.f, a1 = 0.f;
    for (int m = tid; m < 1000; m += 256) {
        float z = zb[b * 1024 + m];
        a0 = fmaf(z, Wc2[m * 2], a0);
        a1 = fmaf(z, Wc2[m * 2 + 1], a1);
    }
#pragma unroll
    for (int off = 1; off < 64; off <<= 1) {
        a0 += __shfl_xor(a0, off);
        a1 += __shfl_xor(a1, off);
    }
    __shared__ float r0[4], r1[4];
    if ((tid & 63) == 0) { r0[tid >> 6] = a0; r1[tid >> 6] = a1; }
    __syncthreads();
    if (tid == 0) {
        out[b * 2 + 0] = r0[0] + r0[1] + r0[2] + r0[3] + bc2[0];
        out[b * 2 + 1] = r1[0] + r1[1] + r1[2] + r1[3] + bc2[1];
    }
}

extern "C" void kernel_launch(void* const* d_in, const int* in_sizes, int n_in,
                              void* d_out, int out_size, void* d_ws, size_t ws_size,
                              hipStream_t stream) {
    (void)in_sizes; (void)n_in; (void)out_size; (void)ws_size;

    const float* x_feat = (const float*)d_in[0];
    const int* node_roi = (const int*)d_in[1];
    const int* ei1 = (const int*)d_in[3];
    const float* ew1 = (const float*)d_in[4];
    const float* x2f = (const float*)d_in[5];
    const int* roi2 = (const int*)d_in[6];
    const int* ei2 = (const int*)d_in[8];
    const float* ew2 = (const float*)d_in[9];
    const float* Wg1 = (const float*)d_in[10];
    const float* bg1 = (const float*)d_in[11];
    const float* Wg2 = (const float*)d_in[12];
    const float* bg2 = (const float*)d_in[13];
    const float* Wr1 = (const float*)d_in[14];
    const float* br1 = (const float*)d_in[15];
    const float* Wr2 = (const float*)d_in[16];
    const float* br2 = (const float*)d_in[17];
    const float* in_proj_w = (const float*)d_in[18];
    const float* in_proj_b = (const float*)d_in[19];
    const float* out_proj_w = (const float*)d_in[20];
    const float* out_proj_b = (const float*)d_in[21];
    const float* ln1_g = (const float*)d_in[22];
    const float* ln1_b = (const float*)d_in[23];
    const float* ff_w1 = (const float*)d_in[24];
    const float* ff_b1 = (const float*)d_in[25];
    const float* ff_w2 = (const float*)d_in[26];
    const float* ff_b2 = (const float*)d_in[27];
    const float* ln2_g = (const float*)d_in[28];
    const float* ln2_b = (const float*)d_in[29];
    const float* Wc1 = (const float*)d_in[30];
    const float* bc1 = (const float*)d_in[31];
    const float* bn_g = (const float*)d_in[32];
    const float* bn_b = (const float*)d_in[33];
    const float* Wc2 = (const float*)d_in[34];
    const float* bc2 = (const float*)d_in[35];

    const int* src1 = ei1;
    const int* dst1 = ei1 + E1v;
    const int* src2 = ei2;
    const int* dst2 = ei2 + E2v;

    float* out = (float*)d_out;
    const int PSZ = BRv * 64;
    float* pooled_out = out + 128;
    float* pooledroi_out = out + 128 + PSZ;
    float* tout_out = out + 128 + 2 * PSZ;
    float* attn_out = out + 128 + 3 * PSZ;

    // ===== workspace layout (floats) =====
    float* W = (float*)d_ws;
    size_t o = 0;
    float* dinv1 = W + o;       o += N1v;
    int* counts1 = (int*)(W + o); o += N1v;
    float* dinv2 = W + o;       o += N2v;
    int* counts2 = (int*)(W + o); o += N2v;
    float* sums1 = W + o;       o += PSZ;
    float* cnt1 = W + o;        o += BRv;
    float* sums2 = W + o;       o += PSZ;
    float* cnt2 = W + o;        o += BRv;
    float* zbuf = W + o;        o += BBv * 1024;
    size_t zone_elems = o;
    int* offs1 = (int*)(W + o); o += N1v;
    int* aux1 = (int*)(W + o);  o += 256;
    int* srcC1 = (int*)(W + o); o += E1v;
    float* normC1 = W + o;      o += E1v;
    int* offs2 = (int*)(W + o); o += N2v;
    int* aux2 = (int*)(W + o);  o += 256;
    int* srcC2 = (int*)(W + o); o += E2v;
    float* normC2 = W + o;      o += E2v;
    float* h1Pf = W + o; size_t h1P_off = o; o += (size_t)N1v * 64;
    float* h1A = W + o; size_t h1A_off = o; o += (size_t)N1v * 64;
    ushort_t* h1P = (ushort_t*)h1Pf;
    size_t p = h1P_off;
    ushort_t* h2P = (ushort_t*)(W + p);  p += (size_t)N2v * 64;
    float* h2A = W + p;  p += (size_t)N2v * 64;
    float* comb = W + p; p += PSZ;
    float* qkvb = W + p; p += (size_t)BRv * 192;
    float* obuf = W + p; p += PSZ;
    float* xbuf = W + p; p += PSZ;
    float* f1 = W + p;   p += PSZ;
    float* WinT = W + p; p += 64 * 192;
    float* WoutT = W + p; p += 64 * 64;
    float* Zp = W + h1A_off;

    dim3 blk(256);

    hipMemsetAsync(W, 0, zone_elems * sizeof(float), stream);

    // ===== branch 1 (node graph): CSR build =====
    k_deg_hist<<<E1v / 256, blk, 0, stream>>>(dst1, ew1, dinv1, counts1, E1v);
    k_dinv<<<N1v / 256, blk, 0, stream>>>(dinv1, N1v);
    k_scan1<<<N1v / 1024, blk, 0, stream>>>(counts1, offs1, aux1, N1v);
    k_scan2<<<1, blk, 0, stream>>>(aux1, N1v / 1024);
    k_scan3<<<N1v / 256, blk, 0, stream>>>(offs1, aux1, counts1, N1v);
    k_fill<<<E1v / 256, blk, 0, stream>>>(src1, dst1, ew1, dinv1, counts1, srcC1, normC1, E1v);
    // layers
    k_gemm_mfma<false><<<2048, blk, 0, stream>>>(x_feat, Wg1, h1P, N1v);
    k_edge_gather2<<<4096, blk, 0, stream>>>(srcC1, normC1, offs1, h1P, dinv1, bg1, h1A, N1v, E1v);
    k_gemm_mfma<true><<<2048, blk, 0, stream>>>(h1A, Wg2, h1P, N1v);
    k_edge_gather2<<<4096, blk, 0, stream>>>(srcC1, normC1, offs1, h1P, dinv1, bg2, h1A, N1v, E1v);
    k_pool_part<<<BBv * 4, blk, 0, stream>>>(h1A, node_roi, sums1, cnt1, N1v / BBv, 4);
    k_pool_fin<<<cdiv(PSZ, 256), blk, 0, stream>>>(sums1, cnt1, pooled_out, PSZ);

    // ===== branch 2 (roi graph): CSR build =====
    k_deg_hist<<<E2v / 256, blk, 0, stream>>>(dst2, ew2, dinv2, counts2, E2v);
    k_dinv<<<cdiv(N2v, 256), blk, 0, stream>>>(dinv2, N2v);
    k_scan1<<<cdiv(N2v, 1024), blk, 0, stream>>>(counts2, offs2, aux2, N2v);
    k_scan2<<<1, blk, 0, stream>>>(aux2, cdiv(N2v, 1024));
    k_scan3<<<cdiv(N2v, 256), blk, 0, stream>>>(offs2, aux2, counts2, N2v);
    k_fill<<<E2v / 256, blk, 0, stream>>>(src2, dst2, ew2, dinv2, counts2, srcC2, normC2, E2v);
    // layers
    k_gemm_rowwave<1, false, false, true><<<cdiv(N2v, 4), blk, 148 * 64 * 4, stream>>>(x2f, Wr1, nullptr, h2P, N2v, 148);
    k_edge_gather2<<<cdiv(N2v, 4), blk, 0, stream>>>(srcC2, normC2, offs2, h2P, dinv2, br1, h2A, N2v, E2v);
    k_gemm_mfma<true><<<148, blk, 0, stream>>>(h2A, Wr2, h2P, N2v);
    k_edge_gather2<<<cdiv(N2v, 4), blk, 0, stream>>>(srcC2, normC2, offs2, h2P, dinv2, br2, h2A, N2v, E2v);
    k_pool_part<<<BBv, blk, 0, stream>>>(h2A, roi2, sums2, cnt2, RRv, 1);
    k_pool_fin2<<<cdiv(PSZ, 256), blk, 0, stream>>>(sums2, cnt2, pooled_out, pooledroi_out, comb, PSZ);

    // ===== transformer =====
    k_transpose<<<cdiv(192 * 64, 256), blk, 0, stream>>>(in_proj_w, WinT, 192, 64);
    k_transpose<<<cdiv(64 * 64, 256), blk, 0, stream>>>(out_proj_w, WoutT, 64, 64);
    k_gemm_rowwave<3, false, false, false><<<cdiv(N2v, 4), blk, 64 * 192 * 4, stream>>>(comb, WinT, in_proj_b, qkvb, N2v, 64);
    k_attn<<<BBv * 4 * 4, blk, 0, stream>>>(qkvb, attn_out, obuf);
    k_ln_gemm<<<cdiv(N2v, 4), blk, 0, stream>>>(obuf, WoutT, out_proj_b, comb, ln1_g, ln1_b, xbuf, N2v);
    k_gemm_rowwave<1, false, true, false><<<cdiv(N2v, 4), blk, 64 * 64 * 4, stream>>>(xbuf, ff_w1, ff_b1, f1, N2v, 64);
    k_ln_gemm<<<cdiv(N2v, 4), blk, 0, stream>>>(f1, ff_w2, ff_b2, xbuf, ln2_g, ln2_b, tout_out, N2v);

    // ===== classifier =====
    k_cls_part<<<512, blk, 0, stream>>>(tout_out, Wc1, Zp);
    k_cls_reduce<<<BBv * 1024 / 256, blk, 0, stream>>>(Zp, bc1, bn_g, bn_b, zbuf);
    k_cls_final<<<BBv, blk, 0, stream>>>(zbuf, Wc2, bc2, out);
}